// Round 1
// baseline (2826.390 us; speedup 1.0000x reference)
//
#include <hip/hip_runtime.h>
#include <hip/hip_bf16.h>
#include <math.h>

// Problem constants
constexpr int Bb  = 2;
constexpr int Ss  = 2048;
constexpr int Dd  = 1024;
constexpr int Hh  = 16;
constexpr int DHh = 64;
constexpr int MLPd = 4096;
constexpr int ROWS = Bb * Ss;        // 4096
constexpr int NC  = Ss / 64;         // 32 chunks of 64
constexpr int BH  = Bb * Hh;         // 32
constexpr float EPS_LN = 1e-6f;
constexpr float KEPS   = 1e-3f;

// ---------------------------------------------------------------------------
// LayerNorm: one block per row of D=1024, 256 threads, 4 elems/thread
// ---------------------------------------------------------------------------
__global__ __launch_bounds__(256) void ln_kernel(const float* __restrict__ x,
                                                 const float* __restrict__ scale,
                                                 const float* __restrict__ bias,
                                                 float* __restrict__ out)
{
    const int row = blockIdx.x;
    const float* xr = x + (size_t)row * Dd;
    float vals[4];
    float sum = 0.f, sumsq = 0.f;
#pragma unroll
    for (int i = 0; i < 4; i++) {
        float v = xr[threadIdx.x + 256 * i];
        vals[i] = v;
        sum += v;
        sumsq += v * v;
    }
#pragma unroll
    for (int off = 32; off > 0; off >>= 1) {
        sum   += __shfl_down(sum, off);
        sumsq += __shfl_down(sumsq, off);
    }
    __shared__ float ssum[4], ssq[4];
    const int wave = threadIdx.x >> 6;
    if ((threadIdx.x & 63) == 0) { ssum[wave] = sum; ssq[wave] = sumsq; }
    __syncthreads();
    const float tot   = ssum[0] + ssum[1] + ssum[2] + ssum[3];
    const float totsq = ssq[0] + ssq[1] + ssq[2] + ssq[3];
    const float mean = tot * (1.f / Dd);
    const float var  = totsq * (1.f / Dd) - mean * mean;
    const float r = rsqrtf(var + EPS_LN);
    float* orow = out + (size_t)row * Dd;
#pragma unroll
    for (int i = 0; i < 4; i++) {
        const int c = threadIdx.x + 256 * i;
        orow[c] = (vals[i] - mean) * r * scale[c] + bias[c];
    }
}

// ---------------------------------------------------------------------------
// Generic fp32 GEMM  C[M,N] = A[M,K] @ Bm[K,N]  (+ epilogue)
// 64x64 tile, BK=16, 256 threads, 4x4 accum per thread.
// mode: 0 none | 1 relu+eps | 2 bias+gelu(tanh) | 3 bias+residual | 4 residual
// ---------------------------------------------------------------------------
__global__ __launch_bounds__(256) void gemm_kernel(const float* __restrict__ A,
                                                   const float* __restrict__ Bm,
                                                   float* __restrict__ C,
                                                   int M, int N, int K,
                                                   const float* __restrict__ bias,
                                                   const float* __restrict__ res,
                                                   int mode)
{
    __shared__ float As[16][65];   // As[k][row]
    __shared__ float Bs[16][65];   // Bs[k][col]
    const int t  = threadIdx.x;
    const int tx = t & 15;         // 0..15 -> col group
    const int ty = t >> 4;         // 0..15 -> row group
    const int row0 = blockIdx.y * 64;
    const int col0 = blockIdx.x * 64;

    const int ka = t & 15;         // A-load k index
    const int ra = t >> 4;         // A-load row base (16 rows/pass, 4 passes)
    const int cb = t & 63;         // B-load col
    const int kb = t >> 6;         // B-load k base (4/pass, 4 passes)

    float acc[4][4] = {};

    for (int k0 = 0; k0 < K; k0 += 16) {
        __syncthreads();
#pragma unroll
        for (int i = 0; i < 4; i++)
            As[ka][ra + 16 * i] = A[(size_t)(row0 + ra + 16 * i) * K + k0 + ka];
#pragma unroll
        for (int i = 0; i < 4; i++)
            Bs[kb + 4 * i][cb] = Bm[(size_t)(k0 + kb + 4 * i) * N + col0 + cb];
        __syncthreads();
#pragma unroll
        for (int kk = 0; kk < 16; kk++) {
            float a[4], b[4];
#pragma unroll
            for (int i = 0; i < 4; i++) a[i] = As[kk][ty * 4 + i];
#pragma unroll
            for (int j = 0; j < 4; j++) b[j] = Bs[kk][tx * 4 + j];
#pragma unroll
            for (int i = 0; i < 4; i++)
#pragma unroll
                for (int j = 0; j < 4; j++) acc[i][j] += a[i] * b[j];
        }
    }

#pragma unroll
    for (int i = 0; i < 4; i++) {
        const int r = row0 + ty * 4 + i;
#pragma unroll
        for (int j = 0; j < 4; j++) {
            const int c = col0 + tx * 4 + j;
            float val = acc[i][j];
            if (mode == 1) {
                val = fmaxf(val, 0.f) + KEPS;
            } else if (mode == 2) {
                val += bias[c];
                const float u = 0.7978845608028654f * (val + 0.044715f * val * val * val);
                val = 0.5f * val * (1.f + tanhf(u));
            } else if (mode == 3) {
                val += bias[c] + res[(size_t)r * N + c];
            } else if (mode == 4) {
                val += res[(size_t)r * N + c];
            }
            C[(size_t)r * N + c] = val;
        }
    }
}

// ---------------------------------------------------------------------------
// Phase A: per-chunk local sums.  KVc[m][d] = sum_s phik[s][m]*v[s][d],
// ksumc[m] = sum_s phik[s][m].   grid = (NC, BH)
// ---------------------------------------------------------------------------
__global__ __launch_bounds__(256) void chunk_kv_kernel(const float* __restrict__ phik,
                                                       const float* __restrict__ v,
                                                       float* __restrict__ kvs,
                                                       float* __restrict__ ksums)
{
    const int c = blockIdx.x, bh = blockIdx.y;
    const int b = bh / Hh, h = bh % Hh;
    __shared__ float sK[64][65];
    __shared__ float sV[64][65];
    const int t = threadIdx.x;
    const int m = t & 63, srow = t >> 6;
#pragma unroll
    for (int i = 0; i < 16; i++) {
        const int s = srow + 4 * i;
        const size_t g = ((size_t)(b * Ss + c * 64 + s) * Hh + h) * DHh + m;
        sK[s][m] = phik[g];
        sV[s][m] = v[g];
    }
    __syncthreads();
    const int tx = t & 15, ty = t >> 4;
    float acc[4][4] = {};
    for (int s = 0; s < 64; s++) {
        float a[4], bb[4];
#pragma unroll
        for (int i = 0; i < 4; i++) a[i] = sK[s][ty * 4 + i];
#pragma unroll
        for (int j = 0; j < 4; j++) bb[j] = sV[s][tx * 4 + j];
#pragma unroll
        for (int i = 0; i < 4; i++)
#pragma unroll
            for (int j = 0; j < 4; j++) acc[i][j] += a[i] * bb[j];
    }
    const size_t base = ((size_t)bh * NC + c) * 4096;
#pragma unroll
    for (int i = 0; i < 4; i++)
#pragma unroll
        for (int j = 0; j < 4; j++)
            kvs[base + (size_t)(ty * 4 + i) * 64 + tx * 4 + j] = acc[i][j];
    if (t < 64) {
        float s_ = 0.f;
        for (int s = 0; s < 64; s++) s_ += sK[s][t];
        ksums[((size_t)bh * NC + c) * 64 + t] = s_;
    }
}

// ---------------------------------------------------------------------------
// Phase B: in-place exclusive prefix scan over chunks (per bh). grid = BH
// ---------------------------------------------------------------------------
__global__ __launch_bounds__(256) void scan_kernel(float* __restrict__ kvs,
                                                   float* __restrict__ ksums)
{
    const int bh = blockIdx.x;
    float run[16] = {};
    for (int c = 0; c < NC; c++) {
        const size_t base = ((size_t)bh * NC + c) * 4096;
#pragma unroll
        for (int i = 0; i < 16; i++) {
            const int e = threadIdx.x + 256 * i;
            const float val = kvs[base + e];
            kvs[base + e] = run[i];
            run[i] += val;
        }
    }
    if (threadIdx.x < 64) {
        float r = 0.f;
        for (int c = 0; c < NC; c++) {
            const size_t idx = ((size_t)bh * NC + c) * 64 + threadIdx.x;
            const float val = ksums[idx];
            ksums[idx] = r;
            r += val;
        }
    }
}

// ---------------------------------------------------------------------------
// Phase C: per-chunk output.
//   Sloc = tril(phiq @ phik^T)      (inclusive diagonal)
//   den[i] = phiq[i]·ksum_excl + rowsum(Sloc[i])
//   out[i] = (Sloc @ v + phiq @ KV_excl) / den[i]
// grid = (NC, BH)
// ---------------------------------------------------------------------------
__global__ __launch_bounds__(256) void attn_out_kernel(const float* __restrict__ phiq,
                                                       const float* __restrict__ phik,
                                                       const float* __restrict__ v,
                                                       const float* __restrict__ kvs,
                                                       const float* __restrict__ ksums,
                                                       float* __restrict__ attn)
{
    const int c = blockIdx.x, bh = blockIdx.y;
    const int b = bh / Hh, h = bh % Hh;
    __shared__ float bufA[64][65];  // phi_q   (kept whole kernel)
    __shared__ float bufB[64][65];  // phi_k, then v
    __shared__ float bufC[64][65];  // Sloc, then KV_excl
    __shared__ float den[64];
    __shared__ float sKsum[64];
    const int t = threadIdx.x;
    const int m = t & 63, srow = t >> 6;
    const int tx = t & 15, ty = t >> 4;

#pragma unroll
    for (int i = 0; i < 16; i++) {
        const int s = srow + 4 * i;
        const size_t g = ((size_t)(b * Ss + c * 64 + s) * Hh + h) * DHh + m;
        bufA[s][m] = phiq[g];
        bufB[s][m] = phik[g];
    }
    if (t < 64) sKsum[t] = ksums[((size_t)bh * NC + c) * 64 + t];
    __syncthreads();

    // Sloc = tril(phi_q @ phi_k^T)
    {
        float acc[4][4] = {};
        for (int mm = 0; mm < 64; mm++) {
            float a[4], bb[4];
#pragma unroll
            for (int i = 0; i < 4; i++) a[i] = bufA[ty * 4 + i][mm];
#pragma unroll
            for (int j = 0; j < 4; j++) bb[j] = bufB[tx * 4 + j][mm];
#pragma unroll
            for (int i = 0; i < 4; i++)
#pragma unroll
                for (int j = 0; j < 4; j++) acc[i][j] += a[i] * bb[j];
        }
#pragma unroll
        for (int i = 0; i < 4; i++)
#pragma unroll
            for (int j = 0; j < 4; j++) {
                const int ii = ty * 4 + i, jj = tx * 4 + j;
                bufC[ii][jj] = (jj <= ii) ? acc[i][j] : 0.f;
            }
    }
    __syncthreads();

    // den
    if (t < 64) {
        float d_ = 0.f;
        for (int mm = 0; mm < 64; mm++) d_ += bufA[t][mm] * sKsum[mm] + bufC[t][mm];
        den[t] = d_;
    }
    __syncthreads();  // everyone done reading phi_k from bufB

    // reload bufB with v
#pragma unroll
    for (int i = 0; i < 16; i++) {
        const int s = srow + 4 * i;
        const size_t g = ((size_t)(b * Ss + c * 64 + s) * Hh + h) * DHh + m;
        bufB[s][m] = v[g];
    }
    __syncthreads();

    float acc[4][4] = {};
    // acc += Sloc @ v
    for (int j = 0; j < 64; j++) {
        float a[4], bb[4];
#pragma unroll
        for (int i = 0; i < 4; i++) a[i] = bufC[ty * 4 + i][j];
#pragma unroll
        for (int jj = 0; jj < 4; jj++) bb[jj] = bufB[j][tx * 4 + jj];
#pragma unroll
        for (int i = 0; i < 4; i++)
#pragma unroll
            for (int jj = 0; jj < 4; jj++) acc[i][jj] += a[i] * bb[jj];
    }
    __syncthreads();  // done with Sloc, overwrite bufC with KV_excl

    {
        const size_t base = ((size_t)bh * NC + c) * 4096;
#pragma unroll
        for (int i = 0; i < 16; i++) {
            const int e = t + 256 * i;
            bufC[e >> 6][e & 63] = kvs[base + e];
        }
    }
    __syncthreads();

    // acc += phi_q @ KV_excl
    for (int mm = 0; mm < 64; mm++) {
        float a[4], bb[4];
#pragma unroll
        for (int i = 0; i < 4; i++) a[i] = bufA[ty * 4 + i][mm];
#pragma unroll
        for (int jj = 0; jj < 4; jj++) bb[jj] = bufC[mm][tx * 4 + jj];
#pragma unroll
        for (int i = 0; i < 4; i++)
#pragma unroll
            for (int jj = 0; jj < 4; jj++) acc[i][jj] += a[i] * bb[jj];
    }

#pragma unroll
    for (int i = 0; i < 4; i++) {
        const int s = c * 64 + ty * 4 + i;
        const float dinv = 1.f / den[ty * 4 + i];
#pragma unroll
        for (int jj = 0; jj < 4; jj++) {
            attn[((size_t)(b * Ss + s) * Hh + h) * DHh + tx * 4 + jj] = acc[i][jj] * dinv;
        }
    }
}

// ---------------------------------------------------------------------------
// Host launch
// ---------------------------------------------------------------------------
extern "C" void kernel_launch(void* const* d_in, const int* in_sizes, int n_in,
                              void* d_out, int out_size, void* d_ws, size_t ws_size,
                              hipStream_t stream)
{
    const float* inputs    = (const float*)d_in[0];
    const float* ln1_scale = (const float*)d_in[1];
    const float* ln1_bias  = (const float*)d_in[2];
    const float* wq        = (const float*)d_in[3];
    const float* wk        = (const float*)d_in[4];
    const float* wv        = (const float*)d_in[5];
    const float* wo        = (const float*)d_in[6];
    const float* ln2_scale = (const float*)d_in[7];
    const float* ln2_bias  = (const float*)d_in[8];
    const float* w1        = (const float*)d_in[9];
    const float* b1        = (const float*)d_in[10];
    const float* w2        = (const float*)d_in[11];
    const float* b2        = (const float*)d_in[12];
    float* out = (float*)d_out;

    // Workspace layout (floats). Reuse: attn<-xln, yln<-q, hbuf<-k.
    float* ws = (float*)d_ws;
    const size_t SZ = (size_t)ROWS * Dd;     // 4M floats
    float* xln   = ws;                       // [4096,1024]; later attn
    float* q     = xln + SZ;                 // phi_q; later yln
    float* k     = q + SZ;                   // phi_k; later hbuf (1024x4096 chunk)
    float* v     = k + SZ;
    float* kvs   = v + SZ;                   // 32*32*4096 = 4M floats
    float* ksums = kvs + (size_t)BH * NC * 4096;  // 32*32*64
    float* x2    = ksums + (size_t)BH * NC * 64;
    float* attn  = xln;
    float* yln   = q;
    float* hbuf  = k;

    // 1. LN1
    ln_kernel<<<ROWS, 256, 0, stream>>>(inputs, ln1_scale, ln1_bias, xln);

    // 2. QKV projections (phi applied to q,k in epilogue)
    {
        dim3 grid(Dd / 64, ROWS / 64);
        gemm_kernel<<<grid, 256, 0, stream>>>(xln, wq, q, ROWS, Dd, Dd, nullptr, nullptr, 1);
        gemm_kernel<<<grid, 256, 0, stream>>>(xln, wk, k, ROWS, Dd, Dd, nullptr, nullptr, 1);
        gemm_kernel<<<grid, 256, 0, stream>>>(xln, wv, v, ROWS, Dd, Dd, nullptr, nullptr, 0);
    }

    // 3-5. Chunked causal linear attention
    {
        dim3 gridA(NC, BH);
        chunk_kv_kernel<<<gridA, 256, 0, stream>>>(k, v, kvs, ksums);
        scan_kernel<<<BH, 256, 0, stream>>>(kvs, ksums);
        attn_out_kernel<<<gridA, 256, 0, stream>>>(q, k, v, kvs, ksums, attn);
    }

    // 6. Output projection + residual -> x2
    {
        dim3 grid(Dd / 64, ROWS / 64);
        gemm_kernel<<<grid, 256, 0, stream>>>(attn, wo, x2, ROWS, Dd, Dd, nullptr, inputs, 4);
    }

    // 7. LN2
    ln_kernel<<<ROWS, 256, 0, stream>>>(x2, ln2_scale, ln2_bias, yln);

    // 8. MLP in 4 row-chunks of 1024 (hbuf reuses k's 16MB)
    for (int ch = 0; ch < 4; ch++) {
        const size_t roff = (size_t)ch * 1024;
        dim3 grid1(MLPd / 64, 1024 / 64);
        gemm_kernel<<<grid1, 256, 0, stream>>>(yln + roff * Dd, w1, hbuf,
                                               1024, MLPd, Dd, b1, nullptr, 2);
        dim3 grid2(Dd / 64, 1024 / 64);
        gemm_kernel<<<grid2, 256, 0, stream>>>(hbuf, w2, out + roff * Dd,
                                               1024, Dd, MLPd, b2, x2 + roff * Dd, 3);
    }
}

// Round 2
// 474.087 us; speedup vs baseline: 5.9617x; 5.9617x over previous
//
#include <hip/hip_runtime.h>
#include <math.h>
#include <stdint.h>

typedef __bf16 bf16;
typedef bf16  bf16x8 __attribute__((ext_vector_type(8)));
typedef float f32x4  __attribute__((ext_vector_type(4)));

// Problem constants
constexpr int Bb  = 2;
constexpr int Ss  = 2048;
constexpr int Dd  = 1024;
constexpr int Hh  = 16;
constexpr int DHh = 64;
constexpr int MLPd = 4096;
constexpr int ROWS = Bb * Ss;        // 4096
constexpr int NC  = Ss / 64;         // 32 chunks of 64
constexpr int BH  = Bb * Hh;         // 32
constexpr float EPS_LN = 1e-6f;
constexpr float KEPS   = 1e-3f;

// ---------------------------------------------------------------------------
// async global->LDS copy, 16B per lane (global_load_lds_dwordx4)
// ---------------------------------------------------------------------------
__device__ __forceinline__ void async_copy16(const bf16* g, bf16* l) {
    __builtin_amdgcn_global_load_lds(
        (__attribute__((address_space(1))) void*)g,
        (__attribute__((address_space(3))) void*)l,
        16, 0, 0);
}

// ---------------------------------------------------------------------------
// LayerNorm: one block per row of D=1024, 256 threads, 4 elems/thread.
// fp32 in -> bf16 out.
// ---------------------------------------------------------------------------
__global__ __launch_bounds__(256) void ln_kernel(const float* __restrict__ x,
                                                 const float* __restrict__ scale,
                                                 const float* __restrict__ bias,
                                                 bf16* __restrict__ out)
{
    const int row = blockIdx.x;
    const float* xr = x + (size_t)row * Dd;
    float vals[4];
    float sum = 0.f, sumsq = 0.f;
#pragma unroll
    for (int i = 0; i < 4; i++) {
        float v = xr[threadIdx.x + 256 * i];
        vals[i] = v;
        sum += v;
        sumsq += v * v;
    }
#pragma unroll
    for (int off = 32; off > 0; off >>= 1) {
        sum   += __shfl_down(sum, off);
        sumsq += __shfl_down(sumsq, off);
    }
    __shared__ float ssum[4], ssq[4];
    const int wave = threadIdx.x >> 6;
    if ((threadIdx.x & 63) == 0) { ssum[wave] = sum; ssq[wave] = sumsq; }
    __syncthreads();
    const float tot   = ssum[0] + ssum[1] + ssum[2] + ssum[3];
    const float totsq = ssq[0] + ssq[1] + ssq[2] + ssq[3];
    const float mean = tot * (1.f / Dd);
    const float var  = totsq * (1.f / Dd) - mean * mean;
    const float r = rsqrtf(var + EPS_LN);
    bf16* orow = out + (size_t)row * Dd;
#pragma unroll
    for (int i = 0; i < 4; i++) {
        const int c = threadIdx.x + 256 * i;
        orow[c] = (bf16)((vals[i] - mean) * r * scale[c] + bias[c]);
    }
}

// ---------------------------------------------------------------------------
// Weight convert + transpose: fp32 in[K][N] -> bf16 out[N][K]
// 256 threads = 32 wide x 8 tall, 32x32 tile via LDS.
// ---------------------------------------------------------------------------
__global__ __launch_bounds__(256) void convert_T(const float* __restrict__ in,
                                                 bf16* __restrict__ out,
                                                 int K, int N)
{
    __shared__ float tile[32][33];
    const int k0 = blockIdx.y * 32, n0 = blockIdx.x * 32;
    const int tx = threadIdx.x & 31, ty = threadIdx.x >> 5;
#pragma unroll
    for (int i = 0; i < 32; i += 8)
        tile[ty + i][tx] = in[(size_t)(k0 + ty + i) * N + n0 + tx];
    __syncthreads();
#pragma unroll
    for (int i = 0; i < 32; i += 8)
        out[(size_t)(n0 + ty + i) * K + k0 + tx] = (bf16)tile[tx][ty + i];
}

// ---------------------------------------------------------------------------
// bf16 MFMA GEMM (m97 structure): C[M,N] = A[M,K] @ B[K,N], B given as BT[N][K].
// 128x128 tile, BK=32, 256 threads = 4 waves in 2x2, each wave 64x64 via
// 4x4 grid of 16x16x32 MFMA. global_load_lds width=16 staging.
// Epilogue modes:
//   EP_PHI:      relu+eps            -> bf16
//   EP_NONE:     none                -> bf16
//   EP_RES:      + res               -> fp32
//   EP_GELU:     + bias, gelu(tanh)  -> bf16
//   EP_BIAS_RES: + bias + res        -> fp32
// ---------------------------------------------------------------------------
enum { EP_PHI = 0, EP_NONE = 1, EP_RES = 2, EP_GELU = 3, EP_BIAS_RES = 4 };

template <int MODE>
__global__ __launch_bounds__(256) void mfma_gemm(const bf16* __restrict__ A,
                                                 const bf16* __restrict__ BT,
                                                 void* __restrict__ Cout,
                                                 int M, int N, int K,
                                                 const float* __restrict__ bias,
                                                 const float* __restrict__ res)
{
    __shared__ bf16 As[128 * 32];
    __shared__ bf16 Bs[128 * 32];
    const int t = threadIdx.x;
    const int wave = t >> 6, lane = t & 63;
    const int row0 = blockIdx.y * 128, col0 = blockIdx.x * 128;
    const int wr = wave >> 1, wc = wave & 1;

    // staging: lane covers row (seg*16 + lane>>2), k-offset (lane&3)*8
    const int lrow = lane >> 2;
    const int lcol = (lane & 3) * 8;

    // fragment indices
    const int m = lane & 15, quad = lane >> 4;

    f32x4 acc[4][4] = {};

    for (int k0 = 0; k0 < K; k0 += 32) {
        __syncthreads();
#pragma unroll
        for (int i = 0; i < 2; i++) {
            const int seg = wave * 2 + i;
            const int r = seg * 16 + lrow;
            async_copy16(A  + (size_t)(row0 + r) * K + k0 + lcol, &As[r * 32 + lcol]);
            async_copy16(BT + (size_t)(col0 + r) * K + k0 + lcol, &Bs[r * 32 + lcol]);
        }
        __syncthreads();

        bf16x8 aF[4], bF[4];
#pragma unroll
        for (int i = 0; i < 4; i++)
            aF[i] = *(const bf16x8*)&As[(wr * 64 + i * 16 + m) * 32 + quad * 8];
#pragma unroll
        for (int j = 0; j < 4; j++)
            bF[j] = *(const bf16x8*)&Bs[(wc * 64 + j * 16 + m) * 32 + quad * 8];
#pragma unroll
        for (int i = 0; i < 4; i++)
#pragma unroll
            for (int j = 0; j < 4; j++)
                acc[i][j] = __builtin_amdgcn_mfma_f32_16x16x32_bf16(
                    aF[i], bF[j], acc[i][j], 0, 0, 0);
    }

    // epilogue: C/D layout col=lane&15, row=quad*4+reg (HW-verified)
#pragma unroll
    for (int i = 0; i < 4; i++) {
#pragma unroll
        for (int j = 0; j < 4; j++) {
#pragma unroll
            for (int r = 0; r < 4; r++) {
                const int row = row0 + wr * 64 + i * 16 + quad * 4 + r;
                const int col = col0 + wc * 64 + j * 16 + m;
                float val = acc[i][j][r];
                if constexpr (MODE == EP_PHI) {
                    val = fmaxf(val, 0.f) + KEPS;
                    ((bf16*)Cout)[(size_t)row * N + col] = (bf16)val;
                } else if constexpr (MODE == EP_NONE) {
                    ((bf16*)Cout)[(size_t)row * N + col] = (bf16)val;
                } else if constexpr (MODE == EP_RES) {
                    ((float*)Cout)[(size_t)row * N + col] = val + res[(size_t)row * N + col];
                } else if constexpr (MODE == EP_GELU) {
                    val += bias[col];
                    const float u = 0.7978845608028654f * (val + 0.044715f * val * val * val);
                    val = 0.5f * val * (1.f + tanhf(u));
                    ((bf16*)Cout)[(size_t)row * N + col] = (bf16)val;
                } else {
                    val += bias[col] + res[(size_t)row * N + col];
                    ((float*)Cout)[(size_t)row * N + col] = val;
                }
            }
        }
    }
}

// ---------------------------------------------------------------------------
// Phase A: per-chunk local sums (fp32 math, bf16 inputs).
// KVc[m][d] = sum_s phik[s][m]*v[s][d], ksumc[m] = sum_s phik[s][m].
// grid = (NC, BH)
// ---------------------------------------------------------------------------
__global__ __launch_bounds__(256) void chunk_kv_kernel(const bf16* __restrict__ phik,
                                                       const bf16* __restrict__ v,
                                                       float* __restrict__ kvs,
                                                       float* __restrict__ ksums)
{
    const int c = blockIdx.x, bh = blockIdx.y;
    const int b = bh / Hh, h = bh % Hh;
    __shared__ float sK[64][65];
    __shared__ float sV[64][65];
    const int t = threadIdx.x;
    const int m = t & 63, srow = t >> 6;
#pragma unroll
    for (int i = 0; i < 16; i++) {
        const int s = srow + 4 * i;
        const size_t g = ((size_t)(b * Ss + c * 64 + s) * Hh + h) * DHh + m;
        sK[s][m] = (float)phik[g];
        sV[s][m] = (float)v[g];
    }
    __syncthreads();
    const int tx = t & 15, ty = t >> 4;
    float acc[4][4] = {};
    for (int s = 0; s < 64; s++) {
        float a[4], bb[4];
#pragma unroll
        for (int i = 0; i < 4; i++) a[i] = sK[s][ty * 4 + i];
#pragma unroll
        for (int j = 0; j < 4; j++) bb[j] = sV[s][tx * 4 + j];
#pragma unroll
        for (int i = 0; i < 4; i++)
#pragma unroll
            for (int j = 0; j < 4; j++) acc[i][j] += a[i] * bb[j];
    }
    const size_t base = ((size_t)bh * NC + c) * 4096;
#pragma unroll
    for (int i = 0; i < 4; i++)
#pragma unroll
        for (int j = 0; j < 4; j++)
            kvs[base + (size_t)(ty * 4 + i) * 64 + tx * 4 + j] = acc[i][j];
    if (t < 64) {
        float s_ = 0.f;
        for (int s = 0; s < 64; s++) s_ += sK[s][t];
        ksums[((size_t)bh * NC + c) * 64 + t] = s_;
    }
}

// ---------------------------------------------------------------------------
// Phase B: in-place exclusive prefix scan over chunks (per bh). grid = BH
// ---------------------------------------------------------------------------
__global__ __launch_bounds__(256) void scan_kernel(float* __restrict__ kvs,
                                                   float* __restrict__ ksums)
{
    const int bh = blockIdx.x;
    float run[16] = {};
    for (int c = 0; c < NC; c++) {
        const size_t base = ((size_t)bh * NC + c) * 4096;
#pragma unroll
        for (int i = 0; i < 16; i++) {
            const int e = threadIdx.x + 256 * i;
            const float val = kvs[base + e];
            kvs[base + e] = run[i];
            run[i] += val;
        }
    }
    if (threadIdx.x < 64) {
        float r = 0.f;
        for (int c = 0; c < NC; c++) {
            const size_t idx = ((size_t)bh * NC + c) * 64 + threadIdx.x;
            const float val = ksums[idx];
            ksums[idx] = r;
            r += val;
        }
    }
}

// ---------------------------------------------------------------------------
// Phase C: per-chunk output (fp32 math, bf16 in/out).
//   Sloc = tril(phiq @ phik^T), den = phiq.ksum_excl + rowsum(Sloc)
//   out = (Sloc @ v + phiq @ KV_excl) / den
// grid = (NC, BH)
// ---------------------------------------------------------------------------
__global__ __launch_bounds__(256) void attn_out_kernel(const bf16* __restrict__ phiq,
                                                       const bf16* __restrict__ phik,
                                                       const bf16* __restrict__ v,
                                                       const float* __restrict__ kvs,
                                                       const float* __restrict__ ksums,
                                                       bf16* __restrict__ attn)
{
    const int c = blockIdx.x, bh = blockIdx.y;
    const int b = bh / Hh, h = bh % Hh;
    __shared__ float bufA[64][65];  // phi_q   (kept whole kernel)
    __shared__ float bufB[64][65];  // phi_k, then v
    __shared__ float bufC[64][65];  // Sloc, then KV_excl
    __shared__ float den[64];
    __shared__ float sKsum[64];
    const int t = threadIdx.x;
    const int m = t & 63, srow = t >> 6;
    const int tx = t & 15, ty = t >> 4;

#pragma unroll
    for (int i = 0; i < 16; i++) {
        const int s = srow + 4 * i;
        const size_t g = ((size_t)(b * Ss + c * 64 + s) * Hh + h) * DHh + m;
        bufA[s][m] = (float)phiq[g];
        bufB[s][m] = (float)phik[g];
    }
    if (t < 64) sKsum[t] = ksums[((size_t)bh * NC + c) * 64 + t];
    __syncthreads();

    // Sloc = tril(phi_q @ phi_k^T)
    {
        float acc[4][4] = {};
        for (int mm = 0; mm < 64; mm++) {
            float a[4], bb[4];
#pragma unroll
            for (int i = 0; i < 4; i++) a[i] = bufA[ty * 4 + i][mm];
#pragma unroll
            for (int j = 0; j < 4; j++) bb[j] = bufB[tx * 4 + j][mm];
#pragma unroll
            for (int i = 0; i < 4; i++)
#pragma unroll
                for (int j = 0; j < 4; j++) acc[i][j] += a[i] * bb[j];
        }
#pragma unroll
        for (int i = 0; i < 4; i++)
#pragma unroll
            for (int j = 0; j < 4; j++) {
                const int ii = ty * 4 + i, jj = tx * 4 + j;
                bufC[ii][jj] = (jj <= ii) ? acc[i][j] : 0.f;
            }
    }
    __syncthreads();

    // den
    if (t < 64) {
        float d_ = 0.f;
        for (int mm = 0; mm < 64; mm++) d_ += bufA[t][mm] * sKsum[mm] + bufC[t][mm];
        den[t] = d_;
    }
    __syncthreads();  // everyone done reading phi_k from bufB

    // reload bufB with v
#pragma unroll
    for (int i = 0; i < 16; i++) {
        const int s = srow + 4 * i;
        const size_t g = ((size_t)(b * Ss + c * 64 + s) * Hh + h) * DHh + m;
        bufB[s][m] = (float)v[g];
    }
    __syncthreads();

    float acc[4][4] = {};
    // acc += Sloc @ v
    for (int j = 0; j < 64; j++) {
        float a[4], bb[4];
#pragma unroll
        for (int i = 0; i < 4; i++) a[i] = bufC[ty * 4 + i][j];
#pragma unroll
        for (int jj = 0; jj < 4; jj++) bb[jj] = bufB[j][tx * 4 + jj];
#pragma unroll
        for (int i = 0; i < 4; i++)
#pragma unroll
            for (int jj = 0; jj < 4; jj++) acc[i][jj] += a[i] * bb[jj];
    }
    __syncthreads();  // done with Sloc, overwrite bufC with KV_excl

    {
        const size_t base = ((size_t)bh * NC + c) * 4096;
#pragma unroll
        for (int i = 0; i < 16; i++) {
            const int e = t + 256 * i;
            bufC[e >> 6][e & 63] = kvs[base + e];
        }
    }
    __syncthreads();

    // acc += phi_q @ KV_excl
    for (int mm = 0; mm < 64; mm++) {
        float a[4], bb[4];
#pragma unroll
        for (int i = 0; i < 4; i++) a[i] = bufA[ty * 4 + i][mm];
#pragma unroll
        for (int jj = 0; jj < 4; jj++) bb[jj] = bufC[mm][tx * 4 + jj];
#pragma unroll
        for (int i = 0; i < 4; i++)
#pragma unroll
            for (int jj = 0; jj < 4; jj++) acc[i][jj] += a[i] * bb[jj];
    }

#pragma unroll
    for (int i = 0; i < 4; i++) {
        const int s = c * 64 + ty * 4 + i;
        const float dinv = 1.f / den[ty * 4 + i];
#pragma unroll
        for (int jj = 0; jj < 4; jj++) {
            attn[((size_t)(b * Ss + s) * Hh + h) * DHh + tx * 4 + jj] =
                (bf16)(acc[i][jj] * dinv);
        }
    }
}

// ---------------------------------------------------------------------------
// Host launch
// ---------------------------------------------------------------------------
extern "C" void kernel_launch(void* const* d_in, const int* in_sizes, int n_in,
                              void* d_out, int out_size, void* d_ws, size_t ws_size,
                              hipStream_t stream)
{
    const float* inputs    = (const float*)d_in[0];
    const float* ln1_scale = (const float*)d_in[1];
    const float* ln1_bias  = (const float*)d_in[2];
    const float* wq        = (const float*)d_in[3];
    const float* wk        = (const float*)d_in[4];
    const float* wv        = (const float*)d_in[5];
    const float* wo        = (const float*)d_in[6];
    const float* ln2_scale = (const float*)d_in[7];
    const float* ln2_bias  = (const float*)d_in[8];
    const float* w1        = (const float*)d_in[9];
    const float* b1        = (const float*)d_in[10];
    const float* w2        = (const float*)d_in[11];
    const float* b2        = (const float*)d_in[12];
    float* out = (float*)d_out;

    // Workspace layout (byte offsets; ws >= 96 MB per baseline usage):
    //  0  MB: xln  bf16 8MB   -> attn bf16
    //  8  MB: q    bf16 8MB   -> yln  bf16
    //  16 MB: k    bf16 8MB  \
    //  24 MB: v    bf16 8MB   > -> hbuf bf16 32MB (16..48MB) after phase C
    //  32 MB: kvs  fp32 16MB /
    //  48 MB: x2   fp32 16MB
    //  64 MB: ksums fp32 256KB
    //  64.25 MB: bf16 transposed weights (24MB) -> end 88.25MB
    char* ws = (char*)d_ws;
    bf16*  xln   = (bf16*)ws;
    bf16*  q     = (bf16*)(ws + (8ull  << 20));
    bf16*  k     = (bf16*)(ws + (16ull << 20));
    bf16*  v     = (bf16*)(ws + (24ull << 20));
    float* kvs   = (float*)(ws + (32ull << 20));
    float* x2    = (float*)(ws + (48ull << 20));
    float* ksums = (float*)(ws + (64ull << 20));
    bf16*  wqT   = (bf16*)(ws + (64ull << 20) + (1ull << 18));
    bf16*  wkT   = wqT + 1024 * 1024;
    bf16*  wvT   = wkT + 1024 * 1024;
    bf16*  woT   = wvT + 1024 * 1024;
    bf16*  w1T   = woT + 1024 * 1024;          // [4096][1024]
    bf16*  w2T   = w1T + 4096 * 1024;          // [1024][4096]
    bf16*  attn  = xln;
    bf16*  yln   = q;
    bf16*  hbuf  = k;                          // 32MB spanning k,v,kvs

    // 0. Weight conversion fp32 [K][N] -> bf16 [N][K]
    convert_T<<<dim3(1024 / 32, 1024 / 32), 256, 0, stream>>>(wq, wqT, 1024, 1024);
    convert_T<<<dim3(1024 / 32, 1024 / 32), 256, 0, stream>>>(wk, wkT, 1024, 1024);
    convert_T<<<dim3(1024 / 32, 1024 / 32), 256, 0, stream>>>(wv, wvT, 1024, 1024);
    convert_T<<<dim3(1024 / 32, 1024 / 32), 256, 0, stream>>>(wo, woT, 1024, 1024);
    convert_T<<<dim3(4096 / 32, 1024 / 32), 256, 0, stream>>>(w1, w1T, 1024, 4096);
    convert_T<<<dim3(1024 / 32, 4096 / 32), 256, 0, stream>>>(w2, w2T, 4096, 1024);

    // 1. LN1
    ln_kernel<<<ROWS, 256, 0, stream>>>(inputs, ln1_scale, ln1_bias, xln);

    // 2. QKV projections (phi applied to q,k in epilogue)
    {
        dim3 grid(1024 / 128, ROWS / 128);
        mfma_gemm<EP_PHI ><<<grid, 256, 0, stream>>>(xln, wqT, q, ROWS, 1024, 1024, nullptr, nullptr);
        mfma_gemm<EP_PHI ><<<grid, 256, 0, stream>>>(xln, wkT, k, ROWS, 1024, 1024, nullptr, nullptr);
        mfma_gemm<EP_NONE><<<grid, 256, 0, stream>>>(xln, wvT, v, ROWS, 1024, 1024, nullptr, nullptr);
    }

    // 3-5. Chunked causal linear attention (fp32 math)
    {
        dim3 gridA(NC, BH);
        chunk_kv_kernel<<<gridA, 256, 0, stream>>>(k, v, kvs, ksums);
        scan_kernel<<<BH, 256, 0, stream>>>(kvs, ksums);
        attn_out_kernel<<<gridA, 256, 0, stream>>>(q, k, v, kvs, ksums, attn);
    }

    // 6. Output projection + residual -> x2 (fp32)
    {
        dim3 grid(1024 / 128, ROWS / 128);
        mfma_gemm<EP_RES><<<grid, 256, 0, stream>>>(attn, woT, x2, ROWS, 1024, 1024, nullptr, inputs);
    }

    // 7. LN2
    ln_kernel<<<ROWS, 256, 0, stream>>>(x2, ln2_scale, ln2_bias, yln);

    // 8. MLP (full 4096 rows, no chunking)
    mfma_gemm<EP_GELU><<<dim3(MLPd / 128, ROWS / 128), 256, 0, stream>>>(
        yln, w1T, hbuf, ROWS, MLPd, 1024, b1, nullptr);
    mfma_gemm<EP_BIAS_RES><<<dim3(1024 / 128, ROWS / 128), 256, 0, stream>>>(
        hbuf, w2T, out, ROWS, 1024, MLPd, b2, x2);
}

// Round 3
// 405.323 us; speedup vs baseline: 6.9732x; 1.1697x over previous
//
#include <hip/hip_runtime.h>
#include <math.h>
#include <stdint.h>

typedef __bf16 bf16;
typedef bf16  bf16x8 __attribute__((ext_vector_type(8)));
typedef float f32x4  __attribute__((ext_vector_type(4)));

// Problem constants
constexpr int Bb  = 2;
constexpr int Ss  = 2048;
constexpr int Dd  = 1024;
constexpr int Hh  = 16;
constexpr int DHh = 64;
constexpr int MLPd = 4096;
constexpr int ROWS = Bb * Ss;        // 4096
constexpr int NC  = Ss / 64;         // 32 chunks of 64
constexpr int BH  = Bb * Hh;         // 32
constexpr float EPS_LN = 1e-6f;
constexpr float KEPS   = 1e-3f;

// ---------------------------------------------------------------------------
// async global->LDS copy, 16B per lane (global_load_lds_dwordx4)
// ---------------------------------------------------------------------------
__device__ __forceinline__ void async_copy16(const bf16* g, bf16* l) {
    __builtin_amdgcn_global_load_lds(
        (__attribute__((address_space(1))) void*)g,
        (__attribute__((address_space(3))) void*)l,
        16, 0, 0);
}

// ---------------------------------------------------------------------------
// LayerNorm: one block per row of D=1024, 256 threads, 4 elems/thread.
// fp32 in -> bf16 out.
// ---------------------------------------------------------------------------
__global__ __launch_bounds__(256) void ln_kernel(const float* __restrict__ x,
                                                 const float* __restrict__ scale,
                                                 const float* __restrict__ bias,
                                                 bf16* __restrict__ out)
{
    const int row = blockIdx.x;
    const float* xr = x + (size_t)row * Dd;
    float vals[4];
    float sum = 0.f, sumsq = 0.f;
#pragma unroll
    for (int i = 0; i < 4; i++) {
        float v = xr[threadIdx.x + 256 * i];
        vals[i] = v;
        sum += v;
        sumsq += v * v;
    }
#pragma unroll
    for (int off = 32; off > 0; off >>= 1) {
        sum   += __shfl_down(sum, off);
        sumsq += __shfl_down(sumsq, off);
    }
    __shared__ float ssum[4], ssq[4];
    const int wave = threadIdx.x >> 6;
    if ((threadIdx.x & 63) == 0) { ssum[wave] = sum; ssq[wave] = sumsq; }
    __syncthreads();
    const float tot   = ssum[0] + ssum[1] + ssum[2] + ssum[3];
    const float totsq = ssq[0] + ssq[1] + ssq[2] + ssq[3];
    const float mean = tot * (1.f / Dd);
    const float var  = totsq * (1.f / Dd) - mean * mean;
    const float r = rsqrtf(var + EPS_LN);
    bf16* orow = out + (size_t)row * Dd;
#pragma unroll
    for (int i = 0; i < 4; i++) {
        const int c = threadIdx.x + 256 * i;
        orow[c] = (bf16)((vals[i] - mean) * r * scale[c] + bias[c]);
    }
}

// ---------------------------------------------------------------------------
// Weight convert + transpose: fp32 in[K][N] -> bf16 out[N][K]
// ---------------------------------------------------------------------------
__global__ __launch_bounds__(256) void convert_T(const float* __restrict__ in,
                                                 bf16* __restrict__ out,
                                                 int K, int N)
{
    __shared__ float tile[32][33];
    const int k0 = blockIdx.y * 32, n0 = blockIdx.x * 32;
    const int tx = threadIdx.x & 31, ty = threadIdx.x >> 5;
#pragma unroll
    for (int i = 0; i < 32; i += 8)
        tile[ty + i][tx] = in[(size_t)(k0 + ty + i) * N + n0 + tx];
    __syncthreads();
#pragma unroll
    for (int i = 0; i < 32; i += 8)
        out[(size_t)(n0 + ty + i) * K + k0 + tx] = (bf16)tile[tx][ty + i];
}

// ---------------------------------------------------------------------------
// bf16 MFMA GEMM: C[M,N] = A[M,K] @ B[K,N], B given as BT[N][K].
// 128 x TN tile (TN = 128 or 64), BK=32, 256 threads = 4 waves (2x2).
// Wave tile: 64 x (TN/2) via 4 x (TN/32) grid of 16x16x32 MFMA.
// Epilogue modes:
//   EP_QKV:      N=3072 fused; thirds 0,1 -> relu+eps (phi), third 2 -> none;
//                routed to Cout/out2/out3 each with row stride 1024. bf16.
//   EP_NONE:     none                -> bf16
//   EP_RES:      + res               -> fp32
//   EP_GELU:     + bias, fast gelu   -> bf16
//   EP_BIAS_RES: + bias + res        -> fp32
// ---------------------------------------------------------------------------
enum { EP_QKV = 0, EP_NONE = 1, EP_RES = 2, EP_GELU = 3, EP_BIAS_RES = 4 };

template <int TN, int MODE>
__global__ __launch_bounds__(256) void mfma_gemm(const bf16* __restrict__ A,
                                                 const bf16* __restrict__ BT,
                                                 void* __restrict__ Cout,
                                                 int M, int N, int K,
                                                 const float* __restrict__ bias,
                                                 const float* __restrict__ res,
                                                 bf16* __restrict__ out2,
                                                 bf16* __restrict__ out3)
{
    constexpr int WCT = TN / 2;     // wave col tile
    constexpr int NJ  = TN / 32;    // col fragments per wave
    __shared__ bf16 As[128 * 32];
    __shared__ bf16 Bs[TN * 32];
    const int t = threadIdx.x;
    const int wave = t >> 6, lane = t & 63;
    const int row0 = blockIdx.y * 128, col0 = blockIdx.x * TN;
    const int wr = wave >> 1, wc = wave & 1;

    // staging: lane covers row (seg*16 + lane>>2), k-offset (lane&3)*8
    const int lrow = lane >> 2;
    const int lcol = (lane & 3) * 8;

    // fragment indices
    const int m = lane & 15, quad = lane >> 4;

    f32x4 acc[4][NJ] = {};

    for (int k0 = 0; k0 < K; k0 += 32) {
        __syncthreads();
#pragma unroll
        for (int i = 0; i < 2; i++) {
            const int r = (wave + 4 * i) * 16 + lrow;
            async_copy16(A + (size_t)(row0 + r) * K + k0 + lcol, &As[r * 32 + lcol]);
        }
#pragma unroll
        for (int i = 0; i < TN / 64; i++) {
            const int r = (wave + 4 * i) * 16 + lrow;
            async_copy16(BT + (size_t)(col0 + r) * K + k0 + lcol, &Bs[r * 32 + lcol]);
        }
        __syncthreads();

        bf16x8 aF[4], bF[NJ];
#pragma unroll
        for (int i = 0; i < 4; i++)
            aF[i] = *(const bf16x8*)&As[(wr * 64 + i * 16 + m) * 32 + quad * 8];
#pragma unroll
        for (int j = 0; j < NJ; j++)
            bF[j] = *(const bf16x8*)&Bs[(wc * WCT + j * 16 + m) * 32 + quad * 8];
#pragma unroll
        for (int i = 0; i < 4; i++)
#pragma unroll
            for (int j = 0; j < NJ; j++)
                acc[i][j] = __builtin_amdgcn_mfma_f32_16x16x32_bf16(
                    aF[i], bF[j], acc[i][j], 0, 0, 0);
    }

    // EP_QKV routing (uniform per block: 128 | 1024, TN | 1024)
    bf16* qkv_dst = nullptr;
    int col_base = col0;
    bool do_phi = false;
    if constexpr (MODE == EP_QKV) {
        const int third = col0 >> 10;
        qkv_dst = (third == 0) ? (bf16*)Cout : (third == 1) ? out2 : out3;
        col_base = col0 & 1023;
        do_phi = (third < 2);
    }

    // epilogue: C/D layout col=lane&15, row=quad*4+reg (HW-verified)
#pragma unroll
    for (int i = 0; i < 4; i++) {
#pragma unroll
        for (int j = 0; j < NJ; j++) {
#pragma unroll
            for (int r = 0; r < 4; r++) {
                const int row = row0 + wr * 64 + i * 16 + quad * 4 + r;
                const int col = col0 + wc * WCT + j * 16 + m;
                float val = acc[i][j][r];
                if constexpr (MODE == EP_QKV) {
                    const int lc = col_base + wc * WCT + j * 16 + m;
                    if (do_phi) val = fmaxf(val, 0.f) + KEPS;
                    qkv_dst[(size_t)row * 1024 + lc] = (bf16)val;
                } else if constexpr (MODE == EP_NONE) {
                    ((bf16*)Cout)[(size_t)row * N + col] = (bf16)val;
                } else if constexpr (MODE == EP_RES) {
                    ((float*)Cout)[(size_t)row * N + col] = val + res[(size_t)row * N + col];
                } else if constexpr (MODE == EP_GELU) {
                    val += bias[col];
                    // gelu(x) = x * sigmoid-ish: x * (1 - 1/(exp(2u)+1)), u = 0.79788456*(x+0.044715 x^3)
                    const float u = 0.7978845608028654f * (val + 0.044715f * val * val * val);
                    const float e = __expf(2.f * u);
                    val = val * (1.f - 1.f / (e + 1.f));
                    ((bf16*)Cout)[(size_t)row * N + col] = (bf16)val;
                } else {
                    val += bias[col] + res[(size_t)row * N + col];
                    ((float*)Cout)[(size_t)row * N + col] = val;
                }
            }
        }
    }
}

// ---------------------------------------------------------------------------
// Phase A: per-chunk local sums (fp32 math, bf16 inputs).
// KVc[m][d] = sum_s phik[s][m]*v[s][d], ksumc[m] = sum_s phik[s][m].
// grid = (NC, BH)
// ---------------------------------------------------------------------------
__global__ __launch_bounds__(256) void chunk_kv_kernel(const bf16* __restrict__ phik,
                                                       const bf16* __restrict__ v,
                                                       float* __restrict__ kvs,
                                                       float* __restrict__ ksums)
{
    const int c = blockIdx.x, bh = blockIdx.y;
    const int b = bh / Hh, h = bh % Hh;
    __shared__ float sK[64][65];
    __shared__ float sV[64][65];
    const int t = threadIdx.x;
    const int m = t & 63, srow = t >> 6;
#pragma unroll
    for (int i = 0; i < 16; i++) {
        const int s = srow + 4 * i;
        const size_t g = ((size_t)(b * Ss + c * 64 + s) * Hh + h) * DHh + m;
        sK[s][m] = (float)phik[g];
        sV[s][m] = (float)v[g];
    }
    __syncthreads();
    const int tx = t & 15, ty = t >> 4;
    float acc[4][4] = {};
    for (int s = 0; s < 64; s++) {
        float a[4], bb[4];
#pragma unroll
        for (int i = 0; i < 4; i++) a[i] = sK[s][ty * 4 + i];
#pragma unroll
        for (int j = 0; j < 4; j++) bb[j] = sV[s][tx * 4 + j];
#pragma unroll
        for (int i = 0; i < 4; i++)
#pragma unroll
            for (int j = 0; j < 4; j++) acc[i][j] += a[i] * bb[j];
    }
    const size_t base = ((size_t)bh * NC + c) * 4096;
#pragma unroll
    for (int i = 0; i < 4; i++)
#pragma unroll
        for (int j = 0; j < 4; j++)
            kvs[base + (size_t)(ty * 4 + i) * 64 + tx * 4 + j] = acc[i][j];
    if (t < 64) {
        float s_ = 0.f;
        for (int s = 0; s < 64; s++) s_ += sK[s][t];
        ksums[((size_t)bh * NC + c) * 64 + t] = s_;
    }
}

// ---------------------------------------------------------------------------
// Phase B: exclusive prefix scan over chunks, element-parallel.
// grid = (4096/256, BH): thread handles one (bh, element) scan of length NC.
// ---------------------------------------------------------------------------
__global__ __launch_bounds__(256) void scan_kernel(float* __restrict__ kvs,
                                                   float* __restrict__ ksums)
{
    const int e  = blockIdx.x * 256 + threadIdx.x;
    const int bh = blockIdx.y;
    float run = 0.f;
#pragma unroll 4
    for (int c = 0; c < NC; c++) {
        const size_t idx = ((size_t)bh * NC + c) * 4096 + e;
        const float val = kvs[idx];
        kvs[idx] = run;
        run += val;
    }
    if (blockIdx.x == 0 && threadIdx.x < 64) {
        float r = 0.f;
        for (int c = 0; c < NC; c++) {
            const size_t idx = ((size_t)bh * NC + c) * 64 + threadIdx.x;
            const float val = ksums[idx];
            ksums[idx] = r;
            r += val;
        }
    }
}

// ---------------------------------------------------------------------------
// Phase C: per-chunk output (fp32 math, bf16 in/out).
//   Sloc = tril(phiq @ phik^T), den = phiq.ksum_excl + rowsum(Sloc)
//   out = (Sloc @ v + phiq @ KV_excl) / den
// grid = (NC, BH)
// ---------------------------------------------------------------------------
__global__ __launch_bounds__(256) void attn_out_kernel(const bf16* __restrict__ phiq,
                                                       const bf16* __restrict__ phik,
                                                       const bf16* __restrict__ v,
                                                       const float* __restrict__ kvs,
                                                       const float* __restrict__ ksums,
                                                       bf16* __restrict__ attn)
{
    const int c = blockIdx.x, bh = blockIdx.y;
    const int b = bh / Hh, h = bh % Hh;
    __shared__ float bufA[64][65];  // phi_q   (kept whole kernel)
    __shared__ float bufB[64][65];  // phi_k, then v
    __shared__ float bufC[64][65];  // Sloc, then KV_excl
    __shared__ float den[64];
    __shared__ float sKsum[64];
    const int t = threadIdx.x;
    const int m = t & 63, srow = t >> 6;
    const int tx = t & 15, ty = t >> 4;

#pragma unroll
    for (int i = 0; i < 16; i++) {
        const int s = srow + 4 * i;
        const size_t g = ((size_t)(b * Ss + c * 64 + s) * Hh + h) * DHh + m;
        bufA[s][m] = (float)phiq[g];
        bufB[s][m] = (float)phik[g];
    }
    if (t < 64) sKsum[t] = ksums[((size_t)bh * NC + c) * 64 + t];
    __syncthreads();

    // Sloc = tril(phi_q @ phi_k^T)
    {
        float acc[4][4] = {};
        for (int mm = 0; mm < 64; mm++) {
            float a[4], bb[4];
#pragma unroll
            for (int i = 0; i < 4; i++) a[i] = bufA[ty * 4 + i][mm];
#pragma unroll
            for (int j = 0; j < 4; j++) bb[j] = bufB[tx * 4 + j][mm];
#pragma unroll
            for (int i = 0; i < 4; i++)
#pragma unroll
                for (int j = 0; j < 4; j++) acc[i][j] += a[i] * bb[j];
        }
#pragma unroll
        for (int i = 0; i < 4; i++)
#pragma unroll
            for (int j = 0; j < 4; j++) {
                const int ii = ty * 4 + i, jj = tx * 4 + j;
                bufC[ii][jj] = (jj <= ii) ? acc[i][j] : 0.f;
            }
    }
    __syncthreads();

    // den
    if (t < 64) {
        float d_ = 0.f;
        for (int mm = 0; mm < 64; mm++) d_ += bufA[t][mm] * sKsum[mm] + bufC[t][mm];
        den[t] = d_;
    }
    __syncthreads();  // everyone done reading phi_k from bufB

    // reload bufB with v
#pragma unroll
    for (int i = 0; i < 16; i++) {
        const int s = srow + 4 * i;
        const size_t g = ((size_t)(b * Ss + c * 64 + s) * Hh + h) * DHh + m;
        bufB[s][m] = (float)v[g];
    }
    __syncthreads();

    float acc[4][4] = {};
    // acc += Sloc @ v
    for (int j = 0; j < 64; j++) {
        float a[4], bb[4];
#pragma unroll
        for (int i = 0; i < 4; i++) a[i] = bufC[ty * 4 + i][j];
#pragma unroll
        for (int jj = 0; jj < 4; jj++) bb[jj] = bufB[j][tx * 4 + jj];
#pragma unroll
        for (int i = 0; i < 4; i++)
#pragma unroll
            for (int jj = 0; jj < 4; jj++) acc[i][jj] += a[i] * bb[jj];
    }
    __syncthreads();  // done with Sloc, overwrite bufC with KV_excl

    {
        const size_t base = ((size_t)bh * NC + c) * 4096;
#pragma unroll
        for (int i = 0; i < 16; i++) {
            const int e = t + 256 * i;
            bufC[e >> 6][e & 63] = kvs[base + e];
        }
    }
    __syncthreads();

    // acc += phi_q @ KV_excl
    for (int mm = 0; mm < 64; mm++) {
        float a[4], bb[4];
#pragma unroll
        for (int i = 0; i < 4; i++) a[i] = bufA[ty * 4 + i][mm];
#pragma unroll
        for (int jj = 0; jj < 4; jj++) bb[jj] = bufC[mm][tx * 4 + jj];
#pragma unroll
        for (int i = 0; i < 4; i++)
#pragma unroll
            for (int jj = 0; jj < 4; jj++) acc[i][jj] += a[i] * bb[jj];
    }

#pragma unroll
    for (int i = 0; i < 4; i++) {
        const int s = c * 64 + ty * 4 + i;
        const float dinv = 1.f / den[ty * 4 + i];
#pragma unroll
        for (int jj = 0; jj < 4; jj++) {
            attn[((size_t)(b * Ss + s) * Hh + h) * DHh + tx * 4 + jj] =
                (bf16)(acc[i][jj] * dinv);
        }
    }
}

// ---------------------------------------------------------------------------
// Host launch
// ---------------------------------------------------------------------------
extern "C" void kernel_launch(void* const* d_in, const int* in_sizes, int n_in,
                              void* d_out, int out_size, void* d_ws, size_t ws_size,
                              hipStream_t stream)
{
    const float* inputs    = (const float*)d_in[0];
    const float* ln1_scale = (const float*)d_in[1];
    const float* ln1_bias  = (const float*)d_in[2];
    const float* wq        = (const float*)d_in[3];
    const float* wk        = (const float*)d_in[4];
    const float* wv        = (const float*)d_in[5];
    const float* wo        = (const float*)d_in[6];
    const float* ln2_scale = (const float*)d_in[7];
    const float* ln2_bias  = (const float*)d_in[8];
    const float* w1        = (const float*)d_in[9];
    const float* b1        = (const float*)d_in[10];
    const float* w2        = (const float*)d_in[11];
    const float* b2        = (const float*)d_in[12];
    float* out = (float*)d_out;

    // Workspace layout (byte offsets):
    //  0  MB: xln  bf16 8MB   -> attn bf16
    //  8  MB: q    bf16 8MB   -> yln  bf16
    //  16 MB: k    bf16 8MB  \
    //  24 MB: v    bf16 8MB   > -> hbuf bf16 32MB (16..48MB) after phase C
    //  32 MB: kvs  fp32 16MB /
    //  48 MB: x2   fp32 16MB
    //  64 MB: ksums fp32 256KB
    //  64.25 MB: bf16 transposed weights (24MB): wqT,wkT,wvT contiguous (fused QKV BT)
    char* ws = (char*)d_ws;
    bf16*  xln   = (bf16*)ws;
    bf16*  q     = (bf16*)(ws + (8ull  << 20));
    bf16*  k     = (bf16*)(ws + (16ull << 20));
    bf16*  v     = (bf16*)(ws + (24ull << 20));
    float* kvs   = (float*)(ws + (32ull << 20));
    float* x2    = (float*)(ws + (48ull << 20));
    float* ksums = (float*)(ws + (64ull << 20));
    bf16*  wqT   = (bf16*)(ws + (64ull << 20) + (1ull << 18));
    bf16*  wkT   = wqT + 1024 * 1024;
    bf16*  wvT   = wkT + 1024 * 1024;
    bf16*  woT   = wvT + 1024 * 1024;
    bf16*  w1T   = woT + 1024 * 1024;          // [4096][1024]
    bf16*  w2T   = w1T + 4096 * 1024;          // [1024][4096]
    bf16*  attn  = xln;
    bf16*  yln   = q;
    bf16*  hbuf  = k;                          // 32MB spanning k,v,kvs

    // 0. Weight conversion fp32 [K][N] -> bf16 [N][K]
    convert_T<<<dim3(1024 / 32, 1024 / 32), 256, 0, stream>>>(wq, wqT, 1024, 1024);
    convert_T<<<dim3(1024 / 32, 1024 / 32), 256, 0, stream>>>(wk, wkT, 1024, 1024);
    convert_T<<<dim3(1024 / 32, 1024 / 32), 256, 0, stream>>>(wv, wvT, 1024, 1024);
    convert_T<<<dim3(1024 / 32, 1024 / 32), 256, 0, stream>>>(wo, woT, 1024, 1024);
    convert_T<<<dim3(4096 / 32, 1024 / 32), 256, 0, stream>>>(w1, w1T, 1024, 4096);
    convert_T<<<dim3(1024 / 32, 4096 / 32), 256, 0, stream>>>(w2, w2T, 4096, 1024);

    // 1. LN1
    ln_kernel<<<ROWS, 256, 0, stream>>>(inputs, ln1_scale, ln1_bias, xln);

    // 2. Fused QKV projection: N=3072 (wqT/wkT/wvT contiguous), phi in epilogue
    mfma_gemm<128, EP_QKV><<<dim3(3072 / 128, ROWS / 128), 256, 0, stream>>>(
        xln, wqT, q, ROWS, 3072, 1024, nullptr, nullptr, k, v);

    // 3-5. Chunked causal linear attention (fp32 math)
    {
        dim3 gridA(NC, BH);
        chunk_kv_kernel<<<gridA, 256, 0, stream>>>(k, v, kvs, ksums);
        scan_kernel<<<dim3(4096 / 256, BH), 256, 0, stream>>>(kvs, ksums);
        attn_out_kernel<<<gridA, 256, 0, stream>>>(q, k, v, kvs, ksums, attn);
    }

    // 6. Output projection + residual -> x2 (fp32), TN=64 for occupancy
    mfma_gemm<64, EP_RES><<<dim3(1024 / 64, ROWS / 128), 256, 0, stream>>>(
        attn, woT, x2, ROWS, 1024, 1024, nullptr, inputs, nullptr, nullptr);

    // 7. LN2
    ln_kernel<<<ROWS, 256, 0, stream>>>(x2, ln2_scale, ln2_bias, yln);

    // 8. MLP
    mfma_gemm<128, EP_GELU><<<dim3(MLPd / 128, ROWS / 128), 256, 0, stream>>>(
        yln, w1T, hbuf, ROWS, MLPd, 1024, b1, nullptr, nullptr, nullptr);
    mfma_gemm<64, EP_BIAS_RES><<<dim3(1024 / 64, ROWS / 128), 256, 0, stream>>>(
        hbuf, w2T, out, ROWS, 1024, MLPd, b2, x2, nullptr, nullptr);
}

// Round 4
// 363.418 us; speedup vs baseline: 7.7772x; 1.1153x over previous
//
#include <hip/hip_runtime.h>
#include <math.h>
#include <stdint.h>

typedef __bf16 bf16;
typedef bf16  bf16x8 __attribute__((ext_vector_type(8)));
typedef float f32x4  __attribute__((ext_vector_type(4)));

// Problem constants
constexpr int Bb  = 2;
constexpr int Ss  = 2048;
constexpr int Dd  = 1024;
constexpr int Hh  = 16;
constexpr int DHh = 64;
constexpr int MLPd = 4096;
constexpr int ROWS = Bb * Ss;        // 4096
constexpr int NC  = Ss / 64;         // 32 chunks of 64
constexpr int BH  = Bb * Hh;         // 32
constexpr float EPS_LN = 1e-6f;
constexpr float KEPS   = 1e-3f;

// ---------------------------------------------------------------------------
// async global->LDS copy, 16B per lane (global_load_lds_dwordx4)
// ---------------------------------------------------------------------------
__device__ __forceinline__ void async_copy16(const bf16* g, bf16* l) {
    __builtin_amdgcn_global_load_lds(
        (__attribute__((address_space(1))) void*)g,
        (__attribute__((address_space(3))) void*)l,
        16, 0, 0);
}

// ---------------------------------------------------------------------------
// LayerNorm: one block per row of D=1024, 256 threads, 4 elems/thread.
// fp32 in -> bf16 out.
// ---------------------------------------------------------------------------
__global__ __launch_bounds__(256) void ln_kernel(const float* __restrict__ x,
                                                 const float* __restrict__ scale,
                                                 const float* __restrict__ bias,
                                                 bf16* __restrict__ out)
{
    const int row = blockIdx.x;
    const float* xr = x + (size_t)row * Dd;
    float vals[4];
    float sum = 0.f, sumsq = 0.f;
#pragma unroll
    for (int i = 0; i < 4; i++) {
        float v = xr[threadIdx.x + 256 * i];
        vals[i] = v;
        sum += v;
        sumsq += v * v;
    }
#pragma unroll
    for (int off = 32; off > 0; off >>= 1) {
        sum   += __shfl_down(sum, off);
        sumsq += __shfl_down(sumsq, off);
    }
    __shared__ float ssum[4], ssq[4];
    const int wave = threadIdx.x >> 6;
    if ((threadIdx.x & 63) == 0) { ssum[wave] = sum; ssq[wave] = sumsq; }
    __syncthreads();
    const float tot   = ssum[0] + ssum[1] + ssum[2] + ssum[3];
    const float totsq = ssq[0] + ssq[1] + ssq[2] + ssq[3];
    const float mean = tot * (1.f / Dd);
    const float var  = totsq * (1.f / Dd) - mean * mean;
    const float r = rsqrtf(var + EPS_LN);
    bf16* orow = out + (size_t)row * Dd;
#pragma unroll
    for (int i = 0; i < 4; i++) {
        const int c = threadIdx.x + 256 * i;
        orow[c] = (bf16)((vals[i] - mean) * r * scale[c] + bias[c]);
    }
}

// ---------------------------------------------------------------------------
// Weight convert + transpose: fp32 in[K][N] -> bf16 out[N][K]
// ---------------------------------------------------------------------------
__global__ __launch_bounds__(256) void convert_T(const float* __restrict__ in,
                                                 bf16* __restrict__ out,
                                                 int K, int N)
{
    __shared__ float tile[32][33];
    const int k0 = blockIdx.y * 32, n0 = blockIdx.x * 32;
    const int tx = threadIdx.x & 31, ty = threadIdx.x >> 5;
#pragma unroll
    for (int i = 0; i < 32; i += 8)
        tile[ty + i][tx] = in[(size_t)(k0 + ty + i) * N + n0 + tx];
    __syncthreads();
#pragma unroll
    for (int i = 0; i < 32; i += 8)
        out[(size_t)(n0 + ty + i) * K + k0 + tx] = (bf16)tile[tx][ty + i];
}

// ---------------------------------------------------------------------------
// bf16 MFMA GEMM: C[M,N] = A[M,K] @ B[K,N], B given as BT[N][K].
// 128 x TN tile (TN = 128 or 64), BK=64, 256 threads = 4 waves (2x2).
// Swizzled LDS: LDS[row][c] = G[row][c ^ (row&7)] (chunk = 8 bf16 = 16B).
// Staging lane t, issue i: row = i*32 + (t>>3), phys chunk t&7, fetches
// global chunk (t&7)^((t>>3)&7).  Fragment read at phys chunk
// (s*4+quad)^(m&7) -> 2-way banks = conflict-free.
// Epilogue modes:
//   EP_QKV:      N=3072 fused; thirds 0,1 -> relu+eps (phi), third 2 -> none;
//                routed to Cout/out2/out3 each with row stride 1024. bf16.
//   EP_NONE:     none                -> bf16
//   EP_RES:      + res               -> fp32
//   EP_GELU:     + bias, fast gelu   -> bf16
//   EP_BIAS_RES: + bias + res        -> fp32
// ---------------------------------------------------------------------------
enum { EP_QKV = 0, EP_NONE = 1, EP_RES = 2, EP_GELU = 3, EP_BIAS_RES = 4 };

template <int TN, int MODE>
__global__ __launch_bounds__(256) void mfma_gemm(const bf16* __restrict__ A,
                                                 const bf16* __restrict__ BT,
                                                 void* __restrict__ Cout,
                                                 int M, int N, int K,
                                                 const float* __restrict__ bias,
                                                 const float* __restrict__ res,
                                                 bf16* __restrict__ out2,
                                                 bf16* __restrict__ out3)
{
    constexpr int WCT = TN / 2;     // wave col tile
    constexpr int NJ  = TN / 32;    // col fragments per wave
    __shared__ bf16 As[128 * 64];
    __shared__ bf16 Bs[TN * 64];
    const int t = threadIdx.x;
    const int wave = t >> 6, lane = t & 63;
    const int row0 = blockIdx.y * 128, col0 = blockIdx.x * TN;
    const int wr = wave >> 1, wc = wave & 1;

    // staging indices (per 32-row region)
    const int srow = t >> 3;                       // 0..31
    const int sgc  = (t & 7) ^ ((t >> 3) & 7);     // swizzled global chunk
    const int sdst = t * 8;                        // LDS elem offset within region

    // fragment indices
    const int m = lane & 15, quad = lane >> 4;
    const int mx7 = m & 7;

    f32x4 acc[4][NJ] = {};

    for (int k0 = 0; k0 < K; k0 += 64) {
        __syncthreads();
#pragma unroll
        for (int i = 0; i < 4; i++) {
            const int r = i * 32 + srow;
            async_copy16(A + (size_t)(row0 + r) * K + k0 + sgc * 8,
                         &As[i * 2048 + sdst]);
        }
#pragma unroll
        for (int i = 0; i < TN / 32; i++) {
            const int r = i * 32 + srow;
            async_copy16(BT + (size_t)(col0 + r) * K + k0 + sgc * 8,
                         &Bs[i * 2048 + sdst]);
        }
        __syncthreads();

#pragma unroll
        for (int s = 0; s < 2; s++) {
            const int pco = ((s * 4 + quad) ^ mx7) * 8;   // phys chunk offset (elems)
            bf16x8 aF[4], bF[NJ];
#pragma unroll
            for (int i = 0; i < 4; i++)
                aF[i] = *(const bf16x8*)&As[(wr * 64 + i * 16 + m) * 64 + pco];
#pragma unroll
            for (int j = 0; j < NJ; j++)
                bF[j] = *(const bf16x8*)&Bs[(wc * WCT + j * 16 + m) * 64 + pco];
#pragma unroll
            for (int i = 0; i < 4; i++)
#pragma unroll
                for (int j = 0; j < NJ; j++)
                    acc[i][j] = __builtin_amdgcn_mfma_f32_16x16x32_bf16(
                        aF[i], bF[j], acc[i][j], 0, 0, 0);
        }
    }

    // EP_QKV routing (uniform per block: 128 | 1024, TN | 1024)
    bf16* qkv_dst = nullptr;
    int col_base = col0;
    bool do_phi = false;
    if constexpr (MODE == EP_QKV) {
        const int third = col0 >> 10;
        qkv_dst = (third == 0) ? (bf16*)Cout : (third == 1) ? out2 : out3;
        col_base = col0 & 1023;
        do_phi = (third < 2);
    }

    // epilogue: C/D layout col=lane&15, row=quad*4+reg (HW-verified)
#pragma unroll
    for (int i = 0; i < 4; i++) {
#pragma unroll
        for (int j = 0; j < NJ; j++) {
#pragma unroll
            for (int r = 0; r < 4; r++) {
                const int row = row0 + wr * 64 + i * 16 + quad * 4 + r;
                const int col = col0 + wc * WCT + j * 16 + m;
                float val = acc[i][j][r];
                if constexpr (MODE == EP_QKV) {
                    const int lc = col_base + wc * WCT + j * 16 + m;
                    if (do_phi) val = fmaxf(val, 0.f) + KEPS;
                    qkv_dst[(size_t)row * 1024 + lc] = (bf16)val;
                } else if constexpr (MODE == EP_NONE) {
                    ((bf16*)Cout)[(size_t)row * N + col] = (bf16)val;
                } else if constexpr (MODE == EP_RES) {
                    ((float*)Cout)[(size_t)row * N + col] = val + res[(size_t)row * N + col];
                } else if constexpr (MODE == EP_GELU) {
                    val += bias[col];
                    const float u = 0.7978845608028654f * (val + 0.044715f * val * val * val);
                    const float e = __expf(2.f * u);
                    val = val * (1.f - 1.f / (e + 1.f));
                    ((bf16*)Cout)[(size_t)row * N + col] = (bf16)val;
                } else {
                    val += bias[col] + res[(size_t)row * N + col];
                    ((float*)Cout)[(size_t)row * N + col] = val;
                }
            }
        }
    }
}

// ---------------------------------------------------------------------------
// Phase A: per-chunk local sums (fp32 math, bf16 inputs).
// KVc[m][d] = sum_s phik[s][m]*v[s][d], ksumc[m] = sum_s phik[s][m].
// grid = (NC, BH)
// ---------------------------------------------------------------------------
__global__ __launch_bounds__(256) void chunk_kv_kernel(const bf16* __restrict__ phik,
                                                       const bf16* __restrict__ v,
                                                       float* __restrict__ kvs,
                                                       float* __restrict__ ksums)
{
    const int c = blockIdx.x, bh = blockIdx.y;
    const int b = bh / Hh, h = bh % Hh;
    __shared__ float sK[64][65];
    __shared__ float sV[64][65];
    const int t = threadIdx.x;
    const int m = t & 63, srow = t >> 6;
#pragma unroll
    for (int i = 0; i < 16; i++) {
        const int s = srow + 4 * i;
        const size_t g = ((size_t)(b * Ss + c * 64 + s) * Hh + h) * DHh + m;
        sK[s][m] = (float)phik[g];
        sV[s][m] = (float)v[g];
    }
    __syncthreads();
    const int tx = t & 15, ty = t >> 4;
    float acc[4][4] = {};
    for (int s = 0; s < 64; s++) {
        float a[4], bb[4];
#pragma unroll
        for (int i = 0; i < 4; i++) a[i] = sK[s][ty * 4 + i];
#pragma unroll
        for (int j = 0; j < 4; j++) bb[j] = sV[s][tx * 4 + j];
#pragma unroll
        for (int i = 0; i < 4; i++)
#pragma unroll
            for (int j = 0; j < 4; j++) acc[i][j] += a[i] * bb[j];
    }
    const size_t base = ((size_t)bh * NC + c) * 4096;
#pragma unroll
    for (int i = 0; i < 4; i++)
#pragma unroll
        for (int j = 0; j < 4; j++)
            kvs[base + (size_t)(ty * 4 + i) * 64 + tx * 4 + j] = acc[i][j];
    if (t < 64) {
        float s_ = 0.f;
        for (int s = 0; s < 64; s++) s_ += sK[s][t];
        ksums[((size_t)bh * NC + c) * 64 + t] = s_;
    }
}

// ---------------------------------------------------------------------------
// Phase B: exclusive prefix scan over chunks, element-parallel.
// grid = (4096/256, BH)
// ---------------------------------------------------------------------------
__global__ __launch_bounds__(256) void scan_kernel(float* __restrict__ kvs,
                                                   float* __restrict__ ksums)
{
    const int e  = blockIdx.x * 256 + threadIdx.x;
    const int bh = blockIdx.y;
    float run = 0.f;
#pragma unroll 4
    for (int c = 0; c < NC; c++) {
        const size_t idx = ((size_t)bh * NC + c) * 4096 + e;
        const float val = kvs[idx];
        kvs[idx] = run;
        run += val;
    }
    if (blockIdx.x == 0 && threadIdx.x < 64) {
        float r = 0.f;
        for (int c = 0; c < NC; c++) {
            const size_t idx = ((size_t)bh * NC + c) * 64 + threadIdx.x;
            const float val = ksums[idx];
            ksums[idx] = r;
            r += val;
        }
    }
}

// ---------------------------------------------------------------------------
// Phase C: per-chunk output (fp32 math, bf16 in/out).
// grid = (NC, BH)
// ---------------------------------------------------------------------------
__global__ __launch_bounds__(256) void attn_out_kernel(const bf16* __restrict__ phiq,
                                                       const bf16* __restrict__ phik,
                                                       const bf16* __restrict__ v,
                                                       const float* __restrict__ kvs,
                                                       const float* __restrict__ ksums,
                                                       bf16* __restrict__ attn)
{
    const int c = blockIdx.x, bh = blockIdx.y;
    const int b = bh / Hh, h = bh % Hh;
    __shared__ float bufA[64][65];  // phi_q   (kept whole kernel)
    __shared__ float bufB[64][65];  // phi_k, then v
    __shared__ float bufC[64][65];  // Sloc, then KV_excl
    __shared__ float den[64];
    __shared__ float sKsum[64];
    const int t = threadIdx.x;
    const int m = t & 63, srow = t >> 6;
    const int tx = t & 15, ty = t >> 4;

#pragma unroll
    for (int i = 0; i < 16; i++) {
        const int s = srow + 4 * i;
        const size_t g = ((size_t)(b * Ss + c * 64 + s) * Hh + h) * DHh + m;
        bufA[s][m] = (float)phiq[g];
        bufB[s][m] = (float)phik[g];
    }
    if (t < 64) sKsum[t] = ksums[((size_t)bh * NC + c) * 64 + t];
    __syncthreads();

    // Sloc = tril(phi_q @ phi_k^T)
    {
        float acc[4][4] = {};
        for (int mm = 0; mm < 64; mm++) {
            float a[4], bb[4];
#pragma unroll
            for (int i = 0; i < 4; i++) a[i] = bufA[ty * 4 + i][mm];
#pragma unroll
            for (int j = 0; j < 4; j++) bb[j] = bufB[tx * 4 + j][mm];
#pragma unroll
            for (int i = 0; i < 4; i++)
#pragma unroll
                for (int j = 0; j < 4; j++) acc[i][j] += a[i] * bb[j];
        }
#pragma unroll
        for (int i = 0; i < 4; i++)
#pragma unroll
            for (int j = 0; j < 4; j++) {
                const int ii = ty * 4 + i, jj = tx * 4 + j;
                bufC[ii][jj] = (jj <= ii) ? acc[i][j] : 0.f;
            }
    }
    __syncthreads();

    // den
    if (t < 64) {
        float d_ = 0.f;
        for (int mm = 0; mm < 64; mm++) d_ += bufA[t][mm] * sKsum[mm] + bufC[t][mm];
        den[t] = d_;
    }
    __syncthreads();

    // reload bufB with v
#pragma unroll
    for (int i = 0; i < 16; i++) {
        const int s = srow + 4 * i;
        const size_t g = ((size_t)(b * Ss + c * 64 + s) * Hh + h) * DHh + m;
        bufB[s][m] = (float)v[g];
    }
    __syncthreads();

    float acc[4][4] = {};
    // acc += Sloc @ v
    for (int j = 0; j < 64; j++) {
        float a[4], bb[4];
#pragma unroll
        for (int i = 0; i < 4; i++) a[i] = bufC[ty * 4 + i][j];
#pragma unroll
        for (int jj = 0; jj < 4; jj++) bb[jj] = bufB[j][tx * 4 + jj];
#pragma unroll
        for (int i = 0; i < 4; i++)
#pragma unroll
            for (int jj = 0; jj < 4; jj++) acc[i][jj] += a[i] * bb[jj];
    }
    __syncthreads();

    {
        const size_t base = ((size_t)bh * NC + c) * 4096;
#pragma unroll
        for (int i = 0; i < 16; i++) {
            const int e = t + 256 * i;
            bufC[e >> 6][e & 63] = kvs[base + e];
        }
    }
    __syncthreads();

    // acc += phi_q @ KV_excl
    for (int mm = 0; mm < 64; mm++) {
        float a[4], bb[4];
#pragma unroll
        for (int i = 0; i < 4; i++) a[i] = bufA[ty * 4 + i][mm];
#pragma unroll
        for (int jj = 0; jj < 4; jj++) bb[jj] = bufC[mm][tx * 4 + jj];
#pragma unroll
        for (int i = 0; i < 4; i++)
#pragma unroll
            for (int jj = 0; jj < 4; jj++) acc[i][jj] += a[i] * bb[jj];
    }

#pragma unroll
    for (int i = 0; i < 4; i++) {
        const int s = c * 64 + ty * 4 + i;
        const float dinv = 1.f / den[ty * 4 + i];
#pragma unroll
        for (int jj = 0; jj < 4; jj++) {
            attn[((size_t)(b * Ss + s) * Hh + h) * DHh + tx * 4 + jj] =
                (bf16)(acc[i][jj] * dinv);
        }
    }
}

// ---------------------------------------------------------------------------
// Host launch
// ---------------------------------------------------------------------------
extern "C" void kernel_launch(void* const* d_in, const int* in_sizes, int n_in,
                              void* d_out, int out_size, void* d_ws, size_t ws_size,
                              hipStream_t stream)
{
    const float* inputs    = (const float*)d_in[0];
    const float* ln1_scale = (const float*)d_in[1];
    const float* ln1_bias  = (const float*)d_in[2];
    const float* wq        = (const float*)d_in[3];
    const float* wk        = (const float*)d_in[4];
    const float* wv        = (const float*)d_in[5];
    const float* wo        = (const float*)d_in[6];
    const float* ln2_scale = (const float*)d_in[7];
    const float* ln2_bias  = (const float*)d_in[8];
    const float* w1        = (const float*)d_in[9];
    const float* b1        = (const float*)d_in[10];
    const float* w2        = (const float*)d_in[11];
    const float* b2        = (const float*)d_in[12];
    float* out = (float*)d_out;

    // Workspace layout (byte offsets):
    //  0  MB: xln  bf16 8MB   -> attn bf16
    //  8  MB: q    bf16 8MB   -> yln  bf16
    //  16 MB: k    bf16 8MB  \
    //  24 MB: v    bf16 8MB   > -> hbuf bf16 32MB (16..48MB) after phase C
    //  32 MB: kvs  fp32 16MB /
    //  48 MB: x2   fp32 16MB
    //  64 MB: ksums fp32 256KB
    //  64.25 MB: bf16 transposed weights (24MB): wqT,wkT,wvT contiguous
    char* ws = (char*)d_ws;
    bf16*  xln   = (bf16*)ws;
    bf16*  q     = (bf16*)(ws + (8ull  << 20));
    bf16*  k     = (bf16*)(ws + (16ull << 20));
    bf16*  v     = (bf16*)(ws + (24ull << 20));
    float* kvs   = (float*)(ws + (32ull << 20));
    float* x2    = (float*)(ws + (48ull << 20));
    float* ksums = (float*)(ws + (64ull << 20));
    bf16*  wqT   = (bf16*)(ws + (64ull << 20) + (1ull << 18));
    bf16*  wkT   = wqT + 1024 * 1024;
    bf16*  wvT   = wkT + 1024 * 1024;
    bf16*  woT   = wvT + 1024 * 1024;
    bf16*  w1T   = woT + 1024 * 1024;          // [4096][1024]
    bf16*  w2T   = w1T + 4096 * 1024;          // [1024][4096]
    bf16*  attn  = xln;
    bf16*  yln   = q;
    bf16*  hbuf  = k;                          // 32MB spanning k,v,kvs

    // 0. Weight conversion fp32 [K][N] -> bf16 [N][K]
    convert_T<<<dim3(1024 / 32, 1024 / 32), 256, 0, stream>>>(wq, wqT, 1024, 1024);
    convert_T<<<dim3(1024 / 32, 1024 / 32), 256, 0, stream>>>(wk, wkT, 1024, 1024);
    convert_T<<<dim3(1024 / 32, 1024 / 32), 256, 0, stream>>>(wv, wvT, 1024, 1024);
    convert_T<<<dim3(1024 / 32, 1024 / 32), 256, 0, stream>>>(wo, woT, 1024, 1024);
    convert_T<<<dim3(4096 / 32, 1024 / 32), 256, 0, stream>>>(w1, w1T, 1024, 4096);
    convert_T<<<dim3(1024 / 32, 4096 / 32), 256, 0, stream>>>(w2, w2T, 4096, 1024);

    // 1. LN1
    ln_kernel<<<ROWS, 256, 0, stream>>>(inputs, ln1_scale, ln1_bias, xln);

    // 2. Fused QKV projection: N=3072 (wqT/wkT/wvT contiguous), phi in epilogue
    mfma_gemm<128, EP_QKV><<<dim3(3072 / 128, ROWS / 128), 256, 0, stream>>>(
        xln, wqT, q, ROWS, 3072, 1024, nullptr, nullptr, k, v);

    // 3-5. Chunked causal linear attention (fp32 math)
    {
        dim3 gridA(NC, BH);
        chunk_kv_kernel<<<gridA, 256, 0, stream>>>(k, v, kvs, ksums);
        scan_kernel<<<dim3(4096 / 256, BH), 256, 0, stream>>>(kvs, ksums);
        attn_out_kernel<<<gridA, 256, 0, stream>>>(q, k, v, kvs, ksums, attn);
    }

    // 6. Output projection + residual -> x2 (fp32), TN=64 for occupancy
    mfma_gemm<64, EP_RES><<<dim3(1024 / 64, ROWS / 128), 256, 0, stream>>>(
        attn, woT, x2, ROWS, 1024, 1024, nullptr, inputs, nullptr, nullptr);

    // 7. LN2
    ln_kernel<<<ROWS, 256, 0, stream>>>(x2, ln2_scale, ln2_bias, yln);

    // 8. MLP
    mfma_gemm<128, EP_GELU><<<dim3(MLPd / 128, ROWS / 128), 256, 0, stream>>>(
        yln, w1T, hbuf, ROWS, MLPd, 1024, b1, nullptr, nullptr, nullptr);
    mfma_gemm<64, EP_BIAS_RES><<<dim3(1024 / 64, ROWS / 128), 256, 0, stream>>>(
        hbuf, w2T, out, ROWS, 1024, MLPd, b2, x2, nullptr, nullptr);
}

// Round 5
// 310.328 us; speedup vs baseline: 9.1078x; 1.1711x over previous
//
#include <hip/hip_runtime.h>
#include <math.h>
#include <stdint.h>

typedef __bf16 bf16;
typedef bf16  bf16x8 __attribute__((ext_vector_type(8)));
typedef float f32x4  __attribute__((ext_vector_type(4)));

// Problem constants
constexpr int Bb  = 2;
constexpr int Ss  = 2048;
constexpr int Dd  = 1024;
constexpr int Hh  = 16;
constexpr int DHh = 64;
constexpr int MLPd = 4096;
constexpr int ROWS = Bb * Ss;        // 4096
constexpr int NC  = Ss / 64;         // 32 chunks of 64
constexpr int BH  = Bb * Hh;         // 32
constexpr float EPS_LN = 1e-6f;
constexpr float KEPS   = 1e-3f;

// ---------------------------------------------------------------------------
// async global->LDS copy, 16B per lane (global_load_lds_dwordx4)
// ---------------------------------------------------------------------------
__device__ __forceinline__ void async_copy16(const bf16* g, bf16* l) {
    __builtin_amdgcn_global_load_lds(
        (__attribute__((address_space(1))) void*)g,
        (__attribute__((address_space(3))) void*)l,
        16, 0, 0);
}

// 64-wide swizzled LDS tile index: LDS[row][chunk^(row&7)] — matches the
// measured-conflict-free GEMM fragment pattern (bank = f(chunk'), rows free).
__device__ __forceinline__ int swz64(int row, int col) {
    return row * 64 + (((col >> 3) ^ row) & 7) * 8 + (col & 7);
}

// ---------------------------------------------------------------------------
// LayerNorm: one block per row of D=1024, 256 threads. fp32 in -> bf16 out.
// ---------------------------------------------------------------------------
__global__ __launch_bounds__(256) void ln_kernel(const float* __restrict__ x,
                                                 const float* __restrict__ scale,
                                                 const float* __restrict__ bias,
                                                 bf16* __restrict__ out)
{
    const int row = blockIdx.x;
    const float* xr = x + (size_t)row * Dd;
    float vals[4];
    float sum = 0.f, sumsq = 0.f;
#pragma unroll
    for (int i = 0; i < 4; i++) {
        float v = xr[threadIdx.x + 256 * i];
        vals[i] = v;
        sum += v;
        sumsq += v * v;
    }
#pragma unroll
    for (int off = 32; off > 0; off >>= 1) {
        sum   += __shfl_down(sum, off);
        sumsq += __shfl_down(sumsq, off);
    }
    __shared__ float ssum[4], ssq[4];
    const int wave = threadIdx.x >> 6;
    if ((threadIdx.x & 63) == 0) { ssum[wave] = sum; ssq[wave] = sumsq; }
    __syncthreads();
    const float tot   = ssum[0] + ssum[1] + ssum[2] + ssum[3];
    const float totsq = ssq[0] + ssq[1] + ssq[2] + ssq[3];
    const float mean = tot * (1.f / Dd);
    const float var  = totsq * (1.f / Dd) - mean * mean;
    const float r = rsqrtf(var + EPS_LN);
    bf16* orow = out + (size_t)row * Dd;
#pragma unroll
    for (int i = 0; i < 4; i++) {
        const int c = threadIdx.x + 256 * i;
        orow[c] = (bf16)((vals[i] - mean) * r * scale[c] + bias[c]);
    }
}

// ---------------------------------------------------------------------------
// Weight convert + transpose: fp32 in[K][N] -> bf16 out[N][K]
// ---------------------------------------------------------------------------
__global__ __launch_bounds__(256) void convert_T(const float* __restrict__ in,
                                                 bf16* __restrict__ out,
                                                 int K, int N)
{
    __shared__ float tile[32][33];
    const int k0 = blockIdx.y * 32, n0 = blockIdx.x * 32;
    const int tx = threadIdx.x & 31, ty = threadIdx.x >> 5;
#pragma unroll
    for (int i = 0; i < 32; i += 8)
        tile[ty + i][tx] = in[(size_t)(k0 + ty + i) * N + n0 + tx];
    __syncthreads();
#pragma unroll
    for (int i = 0; i < 32; i += 8)
        out[(size_t)(n0 + ty + i) * K + k0 + tx] = (bf16)tile[tx][ty + i];
}

// 4x 1024x1024 converts in one dispatch (grid.z selects the weight)
__global__ __launch_bounds__(256) void convert_T4(const float* __restrict__ s0,
                                                  const float* __restrict__ s1,
                                                  const float* __restrict__ s2,
                                                  const float* __restrict__ s3,
                                                  bf16* __restrict__ d0,
                                                  bf16* __restrict__ d1,
                                                  bf16* __restrict__ d2,
                                                  bf16* __restrict__ d3)
{
    const float* in  = (blockIdx.z == 0) ? s0 : (blockIdx.z == 1) ? s1
                     : (blockIdx.z == 2) ? s2 : s3;
    bf16* out        = (blockIdx.z == 0) ? d0 : (blockIdx.z == 1) ? d1
                     : (blockIdx.z == 2) ? d2 : d3;
    __shared__ float tile[32][33];
    const int k0 = blockIdx.y * 32, n0 = blockIdx.x * 32;
    const int tx = threadIdx.x & 31, ty = threadIdx.x >> 5;
#pragma unroll
    for (int i = 0; i < 32; i += 8)
        tile[ty + i][tx] = in[(size_t)(k0 + ty + i) * 1024 + n0 + tx];
    __syncthreads();
#pragma unroll
    for (int i = 0; i < 32; i += 8)
        out[(size_t)(n0 + ty + i) * 1024 + k0 + tx] = (bf16)tile[tx][ty + i];
}

// ---------------------------------------------------------------------------
// bf16 MFMA GEMM: C[M,N] = A[M,K] @ B[K,N], B given as BT[N][K].
// 128 x TN tile, BK deep, 256 threads = 4 waves (2x2).
// Swizzled LDS: LDS[row][c] = G[row][c ^ (row&7)] (chunk = 8 bf16 = 16B).
// ---------------------------------------------------------------------------
enum { EP_QKV = 0, EP_NONE = 1, EP_RES = 2, EP_GELU = 3, EP_BIAS_RES = 4 };

template <int TN, int BK, int MODE>
__global__ __launch_bounds__(256) void mfma_gemm(const bf16* __restrict__ A,
                                                 const bf16* __restrict__ BT,
                                                 void* __restrict__ Cout,
                                                 int M, int N, int K,
                                                 const float* __restrict__ bias,
                                                 const float* __restrict__ res,
                                                 bf16* __restrict__ out2,
                                                 bf16* __restrict__ out3)
{
    constexpr int WCT = TN / 2;      // wave col tile
    constexpr int NJ  = TN / 32;     // col fragments per wave
    constexpr int NS  = BK / 32;     // MFMA k-steps per tile
    constexpr int CPR = BK / 8;      // 16B chunks per row
    constexpr int RPI = 2048 / BK;   // rows staged per issue (256 thr x 16B)
    __shared__ bf16 As[128 * BK];
    __shared__ bf16 Bs[TN * BK];
    const int t = threadIdx.x;
    const int wave = t >> 6, lane = t & 63;
    const int row0 = blockIdx.y * 128, col0 = blockIdx.x * TN;
    const int wr = wave >> 1, wc = wave & 1;

    // staging indices
    const int srow = t / CPR;                      // row within issue group
    const int gch  = (t % CPR) ^ (srow & 7);       // swizzled global chunk
    const int sdst = t * 8;                        // LDS elem offset per issue

    // fragment indices
    const int m = lane & 15, quad = lane >> 4;
    const int mx7 = m & 7;

    f32x4 acc[4][NJ] = {};

    for (int k0 = 0; k0 < K; k0 += BK) {
        __syncthreads();
#pragma unroll
        for (int i = 0; i < 128 / RPI; i++) {
            const int r = i * RPI + srow;
            async_copy16(A + (size_t)(row0 + r) * K + k0 + gch * 8,
                         &As[i * 2048 + sdst]);
        }
#pragma unroll
        for (int i = 0; i < TN / RPI; i++) {
            const int r = i * RPI + srow;
            async_copy16(BT + (size_t)(col0 + r) * K + k0 + gch * 8,
                         &Bs[i * 2048 + sdst]);
        }
        __syncthreads();

#pragma unroll
        for (int s = 0; s < NS; s++) {
            const int pco = ((s * 4 + quad) ^ mx7) * 8;   // phys chunk offset
            bf16x8 aF[4], bF[NJ];
#pragma unroll
            for (int i = 0; i < 4; i++)
                aF[i] = *(const bf16x8*)&As[(wr * 64 + i * 16 + m) * BK + pco];
#pragma unroll
            for (int j = 0; j < NJ; j++)
                bF[j] = *(const bf16x8*)&Bs[(wc * WCT + j * 16 + m) * BK + pco];
#pragma unroll
            for (int i = 0; i < 4; i++)
#pragma unroll
                for (int j = 0; j < NJ; j++)
                    acc[i][j] = __builtin_amdgcn_mfma_f32_16x16x32_bf16(
                        aF[i], bF[j], acc[i][j], 0, 0, 0);
        }
    }

    // EP_QKV routing (uniform per block: 128 | 1024, TN | 1024)
    bf16* qkv_dst = nullptr;
    int col_base = col0;
    bool do_phi = false;
    if constexpr (MODE == EP_QKV) {
        const int third = col0 >> 10;
        qkv_dst = (third == 0) ? (bf16*)Cout : (third == 1) ? out2 : out3;
        col_base = col0 & 1023;
        do_phi = (third < 2);
    }

    // epilogue: C/D layout col=lane&15, row=quad*4+reg (HW-verified)
#pragma unroll
    for (int i = 0; i < 4; i++) {
#pragma unroll
        for (int j = 0; j < NJ; j++) {
#pragma unroll
            for (int r = 0; r < 4; r++) {
                const int row = row0 + wr * 64 + i * 16 + quad * 4 + r;
                const int col = col0 + wc * WCT + j * 16 + m;
                float val = acc[i][j][r];
                if constexpr (MODE == EP_QKV) {
                    const int lc = col_base + wc * WCT + j * 16 + m;
                    if (do_phi) val = fmaxf(val, 0.f) + KEPS;
                    qkv_dst[(size_t)row * 1024 + lc] = (bf16)val;
                } else if constexpr (MODE == EP_NONE) {
                    ((bf16*)Cout)[(size_t)row * N + col] = (bf16)val;
                } else if constexpr (MODE == EP_RES) {
                    ((float*)Cout)[(size_t)row * N + col] = val + res[(size_t)row * N + col];
                } else if constexpr (MODE == EP_GELU) {
                    val += bias[col];
                    const float u = 0.7978845608028654f * (val + 0.044715f * val * val * val);
                    const float e = __expf(2.f * u);
                    val = val * (1.f - 1.f / (e + 1.f));
                    ((bf16*)Cout)[(size_t)row * N + col] = (bf16)val;
                } else {
                    val += bias[col] + res[(size_t)row * N + col];
                    ((float*)Cout)[(size_t)row * N + col] = val;
                }
            }
        }
    }
}

// ---------------------------------------------------------------------------
// Phase A (MFMA): KV[m][d] = sum_s phik[s][m]*v[s][d]; ksum[m] = sum_s phik[s][m]
// A-operand Kt[m][s] (transposed), B-operand Vt[d][s] (transposed). grid=(NC,BH)
// ---------------------------------------------------------------------------
__global__ __launch_bounds__(256) void chunk_kv_kernel(const bf16* __restrict__ phik,
                                                       const bf16* __restrict__ v,
                                                       float* __restrict__ kvs,
                                                       float* __restrict__ ksums)
{
    const int c = blockIdx.x, bh = blockIdx.y;
    const int b = bh >> 4, h = bh & 15;
    __shared__ bf16 Kt[64 * 64];   // [m][s]
    __shared__ bf16 Vt[64 * 64];   // [d][s]
    const int t = threadIdx.x;
    const int wave = t >> 6, lane = t & 63;
    const int m16 = lane & 15, quad = lane >> 4;
    const int wr = wave >> 1, wc = wave & 1;
    const int f = t & 63, s4 = t >> 6;

#pragma unroll
    for (int i = 0; i < 16; i++) {
        const int s = s4 + 4 * i;
        const size_t g = ((size_t)((b * Ss + c * 64 + s) * Hh + h)) * DHh + f;
        Kt[swz64(f, s)] = phik[g];
        Vt[swz64(f, s)] = v[g];
    }
    __syncthreads();

    f32x4 acc[2][2] = {};
#pragma unroll
    for (int ks = 0; ks < 2; ks++) {
        bf16x8 aF[2], bF[2];
#pragma unroll
        for (int i = 0; i < 2; i++)
            aF[i] = *(const bf16x8*)&Kt[swz64(wr * 32 + i * 16 + m16, ks * 32 + quad * 8)];
#pragma unroll
        for (int j = 0; j < 2; j++)
            bF[j] = *(const bf16x8*)&Vt[swz64(wc * 32 + j * 16 + m16, ks * 32 + quad * 8)];
#pragma unroll
        for (int i = 0; i < 2; i++)
#pragma unroll
            for (int j = 0; j < 2; j++)
                acc[i][j] = __builtin_amdgcn_mfma_f32_16x16x32_bf16(
                    aF[i], bF[j], acc[i][j], 0, 0, 0);
    }

    const size_t base = ((size_t)bh * NC + c) * 4096;
#pragma unroll
    for (int i = 0; i < 2; i++)
#pragma unroll
        for (int j = 0; j < 2; j++)
#pragma unroll
            for (int r = 0; r < 4; r++) {
                const int mrow = wr * 32 + i * 16 + quad * 4 + r;
                const int dcol = wc * 32 + j * 16 + m16;
                kvs[base + mrow * 64 + dcol] = acc[i][j][r];
            }

    if (t < 64) {
        float s_ = 0.f;
#pragma unroll
        for (int p = 0; p < 8; p++) {
            bf16x8 k8 = *(const bf16x8*)&Kt[t * 64 + p * 8];
#pragma unroll
            for (int e = 0; e < 8; e++) s_ += (float)k8[e];
        }
        ksums[((size_t)bh * NC + c) * 64 + t] = s_;
    }
}

// ---------------------------------------------------------------------------
// Phase B: exclusive prefix scan over chunks, element-parallel.
// ---------------------------------------------------------------------------
__global__ __launch_bounds__(256) void scan_kernel(float* __restrict__ kvs,
                                                   float* __restrict__ ksums)
{
    const int e  = blockIdx.x * 256 + threadIdx.x;
    const int bh = blockIdx.y;
    float run = 0.f;
#pragma unroll 4
    for (int c = 0; c < NC; c++) {
        const size_t idx = ((size_t)bh * NC + c) * 4096 + e;
        const float val = kvs[idx];
        kvs[idx] = run;
        run += val;
    }
    if (blockIdx.x == 0 && threadIdx.x < 64) {
        float r = 0.f;
        for (int c = 0; c < NC; c++) {
            const size_t idx = ((size_t)bh * NC + c) * 64 + threadIdx.x;
            const float val = ksums[idx];
            ksums[idx] = r;
            r += val;
        }
    }
}

// ---------------------------------------------------------------------------
// Phase C (MFMA): per-chunk output.
//   S = tril(phiq @ phik^T)  (MFMA, K=features)
//   den[i] = phiq[i].ksum_excl + rowsum(S[i])
//   out = (S @ v + phiq @ KV_excl) / den
// grid = (NC, BH)
// ---------------------------------------------------------------------------
__global__ __launch_bounds__(256) void attn_out_kernel(const bf16* __restrict__ phiq,
                                                       const bf16* __restrict__ phik,
                                                       const bf16* __restrict__ v,
                                                       const float* __restrict__ kvs,
                                                       const float* __restrict__ ksums,
                                                       bf16* __restrict__ attn)
{
    const int c = blockIdx.x, bh = blockIdx.y;
    const int b = bh >> 4, h = bh & 15;
    __shared__ bf16 Qs [64 * 64];  // phiq [s][f]
    __shared__ bf16 KVb[64 * 64];  // phik [s'][f] -> then Vt [d][s']
    __shared__ bf16 Sm [64 * 64];  // S [row][col]
    __shared__ bf16 KVt[64 * 64];  // KV_excl^T [d][m]
    __shared__ float ksm[64], den[64];
    const int t = threadIdx.x;
    const int wave = t >> 6, lane = t & 63;
    const int m16 = lane & 15, quad = lane >> 4;
    const int wr = wave >> 1, wc = wave & 1;
    const int f = t & 63, s4 = t >> 6;

#pragma unroll
    for (int i = 0; i < 16; i++) {
        const int s = s4 + 4 * i;
        const size_t g = ((size_t)((b * Ss + c * 64 + s) * Hh + h)) * DHh + f;
        Qs [swz64(s, f)] = phiq[g];
        KVb[swz64(s, f)] = phik[g];
    }
    if (t < 64) ksm[t] = ksums[((size_t)bh * NC + c) * 64 + t];
    __syncthreads();

    // S = phiq @ phik^T
    f32x4 sacc[2][2] = {};
#pragma unroll
    for (int ks = 0; ks < 2; ks++) {
        bf16x8 aF[2], bF[2];
#pragma unroll
        for (int i = 0; i < 2; i++)
            aF[i] = *(const bf16x8*)&Qs [swz64(wr * 32 + i * 16 + m16, ks * 32 + quad * 8)];
#pragma unroll
        for (int j = 0; j < 2; j++)
            bF[j] = *(const bf16x8*)&KVb[swz64(wc * 32 + j * 16 + m16, ks * 32 + quad * 8)];
#pragma unroll
        for (int i = 0; i < 2; i++)
#pragma unroll
            for (int j = 0; j < 2; j++)
                sacc[i][j] = __builtin_amdgcn_mfma_f32_16x16x32_bf16(
                    aF[i], bF[j], sacc[i][j], 0, 0, 0);
    }
    // mask (tril, inclusive diag) + store S
#pragma unroll
    for (int i = 0; i < 2; i++)
#pragma unroll
        for (int j = 0; j < 2; j++)
#pragma unroll
            for (int r = 0; r < 4; r++) {
                const int row = wr * 32 + i * 16 + quad * 4 + r;
                const int col = wc * 32 + j * 16 + m16;
                Sm[swz64(row, col)] = (bf16)((col <= row) ? sacc[i][j][r] : 0.f);
            }
    __syncthreads();  // S complete; KVb free for Vt

    // stage Vt[d][s'] and KVt[d][m]
#pragma unroll
    for (int i = 0; i < 16; i++) {
        const int s = s4 + 4 * i;
        const size_t g = ((size_t)((b * Ss + c * 64 + s) * Hh + h)) * DHh + f;
        KVb[swz64(f, s)] = v[g];
    }
    {
        const size_t base = ((size_t)bh * NC + c) * 4096;
#pragma unroll
        for (int i = 0; i < 16; i++) {
            const int e = t + 256 * i;
            KVt[swz64(e & 63, e >> 6)] = (bf16)kvs[base + e];
        }
    }
    __syncthreads();

    // den (physical-order row scans; Sm rowsum is order-free)
    if (t < 64) {
        float d_ = 0.f;
#pragma unroll
        for (int p = 0; p < 8; p++) {
            const int gc = (p ^ (t & 7)) * 8;
            bf16x8 q8 = *(const bf16x8*)&Qs[t * 64 + p * 8];
            bf16x8 s8 = *(const bf16x8*)&Sm[t * 64 + p * 8];
#pragma unroll
            for (int e = 0; e < 8; e++)
                d_ += (float)q8[e] * ksm[gc + e] + (float)s8[e];
        }
        den[t] = d_;
    }

    // O = S @ v + phiq @ KV_excl
    f32x4 oacc[2][2] = {};
#pragma unroll
    for (int ks = 0; ks < 2; ks++) {
        bf16x8 aF[2], bF[2];
#pragma unroll
        for (int i = 0; i < 2; i++)
            aF[i] = *(const bf16x8*)&Sm [swz64(wr * 32 + i * 16 + m16, ks * 32 + quad * 8)];
#pragma unroll
        for (int j = 0; j < 2; j++)
            bF[j] = *(const bf16x8*)&KVb[swz64(wc * 32 + j * 16 + m16, ks * 32 + quad * 8)];
#pragma unroll
        for (int i = 0; i < 2; i++)
#pragma unroll
            for (int j = 0; j < 2; j++)
                oacc[i][j] = __builtin_amdgcn_mfma_f32_16x16x32_bf16(
                    aF[i], bF[j], oacc[i][j], 0, 0, 0);
    }
#pragma unroll
    for (int ks = 0; ks < 2; ks++) {
        bf16x8 aF[2], bF[2];
#pragma unroll
        for (int i = 0; i < 2; i++)
            aF[i] = *(const bf16x8*)&Qs [swz64(wr * 32 + i * 16 + m16, ks * 32 + quad * 8)];
#pragma unroll
        for (int j = 0; j < 2; j++)
            bF[j] = *(const bf16x8*)&KVt[swz64(wc * 32 + j * 16 + m16, ks * 32 + quad * 8)];
#pragma unroll
        for (int i = 0; i < 2; i++)
#pragma unroll
            for (int j = 0; j < 2; j++)
                oacc[i][j] = __builtin_amdgcn_mfma_f32_16x16x32_bf16(
                    aF[i], bF[j], oacc[i][j], 0, 0, 0);
    }
    __syncthreads();  // den ready

#pragma unroll
    for (int i = 0; i < 2; i++) {
#pragma unroll
        for (int r = 0; r < 4; r++) {
            const int row = wr * 32 + i * 16 + quad * 4 + r;
            const float dinv = 1.f / den[row];
#pragma unroll
            for (int j = 0; j < 2; j++) {
                const int col = wc * 32 + j * 16 + m16;
                attn[((size_t)((b * Ss + c * 64 + row) * Hh + h)) * DHh + col] =
                    (bf16)(oacc[i][j][r] * dinv);
            }
        }
    }
}

// ---------------------------------------------------------------------------
// Host launch
// ---------------------------------------------------------------------------
extern "C" void kernel_launch(void* const* d_in, const int* in_sizes, int n_in,
                              void* d_out, int out_size, void* d_ws, size_t ws_size,
                              hipStream_t stream)
{
    const float* inputs    = (const float*)d_in[0];
    const float* ln1_scale = (const float*)d_in[1];
    const float* ln1_bias  = (const float*)d_in[2];
    const float* wq        = (const float*)d_in[3];
    const float* wk        = (const float*)d_in[4];
    const float* wv        = (const float*)d_in[5];
    const float* wo        = (const float*)d_in[6];
    const float* ln2_scale = (const float*)d_in[7];
    const float* ln2_bias  = (const float*)d_in[8];
    const float* w1        = (const float*)d_in[9];
    const float* b1        = (const float*)d_in[10];
    const float* w2        = (const float*)d_in[11];
    const float* b2        = (const float*)d_in[12];
    float* out = (float*)d_out;

    // Workspace layout (byte offsets):
    //  0  MB: xln  bf16 8MB   -> attn bf16
    //  8  MB: q    bf16 8MB   -> yln  bf16
    //  16 MB: k    bf16 8MB  \
    //  24 MB: v    bf16 8MB   > -> hbuf bf16 32MB (16..48MB) after phase C
    //  32 MB: kvs  fp32 16MB /
    //  48 MB: x2   fp32 16MB
    //  64 MB: ksums fp32 256KB
    //  64.25 MB: bf16 transposed weights (24MB): wqT,wkT,wvT contiguous
    char* ws = (char*)d_ws;
    bf16*  xln   = (bf16*)ws;
    bf16*  q     = (bf16*)(ws + (8ull  << 20));
    bf16*  k     = (bf16*)(ws + (16ull << 20));
    bf16*  v     = (bf16*)(ws + (24ull << 20));
    float* kvs   = (float*)(ws + (32ull << 20));
    float* x2    = (float*)(ws + (48ull << 20));
    float* ksums = (float*)(ws + (64ull << 20));
    bf16*  wqT   = (bf16*)(ws + (64ull << 20) + (1ull << 18));
    bf16*  wkT   = wqT + 1024 * 1024;
    bf16*  wvT   = wkT + 1024 * 1024;
    bf16*  woT   = wvT + 1024 * 1024;
    bf16*  w1T   = woT + 1024 * 1024;          // [4096][1024]
    bf16*  w2T   = w1T + 4096 * 1024;          // [1024][4096]
    bf16*  attn  = xln;
    bf16*  yln   = q;
    bf16*  hbuf  = k;                          // 32MB spanning k,v,kvs

    // 0. Weight conversion fp32 [K][N] -> bf16 [N][K]  (3 dispatches)
    convert_T4<<<dim3(32, 32, 4), 256, 0, stream>>>(wq, wk, wv, wo, wqT, wkT, wvT, woT);
    convert_T<<<dim3(4096 / 32, 1024 / 32), 256, 0, stream>>>(w1, w1T, 1024, 4096);
    convert_T<<<dim3(1024 / 32, 4096 / 32), 256, 0, stream>>>(w2, w2T, 4096, 1024);

    // 1. LN1
    ln_kernel<<<ROWS, 256, 0, stream>>>(inputs, ln1_scale, ln1_bias, xln);

    // 2. Fused QKV projection: N=3072 (wqT/wkT/wvT contiguous), phi in epilogue
    mfma_gemm<128, 64, EP_QKV><<<dim3(3072 / 128, ROWS / 128), 256, 0, stream>>>(
        xln, wqT, q, ROWS, 3072, 1024, nullptr, nullptr, k, v);

    // 3-5. Chunked causal linear attention (MFMA phases A and C)
    {
        dim3 gridA(NC, BH);
        chunk_kv_kernel<<<gridA, 256, 0, stream>>>(k, v, kvs, ksums);
        scan_kernel<<<dim3(4096 / 256, BH), 256, 0, stream>>>(kvs, ksums);
        attn_out_kernel<<<gridA, 256, 0, stream>>>(q, k, v, kvs, ksums, attn);
    }

    // 6. Output projection + residual -> x2 (fp32), TN=64 BK=128
    mfma_gemm<64, 128, EP_RES><<<dim3(1024 / 64, ROWS / 128), 256, 0, stream>>>(
        attn, woT, x2, ROWS, 1024, 1024, nullptr, inputs, nullptr, nullptr);

    // 7. LN2
    ln_kernel<<<ROWS, 256, 0, stream>>>(x2, ln2_scale, ln2_bias, yln);

    // 8. MLP
    mfma_gemm<128, 64, EP_GELU><<<dim3(MLPd / 128, ROWS / 128), 256, 0, stream>>>(
        yln, w1T, hbuf, ROWS, MLPd, 1024, b1, nullptr, nullptr, nullptr);
    mfma_gemm<64, 128, EP_BIAS_RES><<<dim3(1024 / 64, ROWS / 128), 256, 0, stream>>>(
        hbuf, w2T, out, ROWS, 1024, MLPd, b2, x2, nullptr, nullptr);
}